// Round 1
// baseline (1007.982 us; speedup 1.0000x reference)
//
#include <hip/hip_runtime.h>
#include <hip/hip_bf16.h>

using bf16 = __hip_bfloat16;

// ---- problem constants (from reference) ----
constexpr int NT = 2000, NW = 50000, ND = 20000;
constexpr int E_TT = 128000, E_WT = 256000, E_TD = 320000, E_WD = 320000;
constexpr float INV_SQRT_DK = 0.17677669529663687f;  // 1/sqrt(32)

// =====================================================================
// fold kernel: Wf[:, h*32+o] = sum_d Wsrc[:, h*32+d] * A[h,d,o]
//              bf[h*32+o]    = sum_d bsrc[h*32+d]    * A[h,d,o]
// folds: f = rel*2 + isV;  rel 0=tt,1=wt,2=td,3=wd; ntype: tt/td->topic(0), wt/wd->word(1)
// grid = 8 folds * 8 row-chunks of 32, block = 256
// =====================================================================
__global__ __launch_bounds__(256) void fold_kernel(
    const float* __restrict__ Wk, const float* __restrict__ bk,
    const float* __restrict__ Wv, const float* __restrict__ bv,
    const float* __restrict__ rel_att, const float* __restrict__ rel_msg,
    float* __restrict__ foldW, float* __restrict__ foldb)
{
    const int f = blockIdx.x >> 3;
    const int chunk = blockIdx.x & 7;
    const int rel = f >> 1;
    const int isV = f & 1;
    const int ntype = (rel == 1 || rel == 3) ? 1 : 0;
    const float* Wsrc = (isV ? Wv : Wk) + ntype * 65536;
    const float* bsrc = (isV ? bv : bk) + ntype * 256;
    const float* A    = (isV ? rel_msg : rel_att) + rel * 8192;  // [8][32][32]
    float* Wdst = foldW + f * 65536;
    float* bdst = foldb + f * 256;

    __shared__ float Wsh[32][256];
    const int tid = threadIdx.x;
    for (int i = 0; i < 32; ++i)
        Wsh[i][tid] = Wsrc[(chunk * 32 + i) * 256 + tid];
    __syncthreads();

    const int h = tid >> 5, o = tid & 31;
    float a[32];
    #pragma unroll
    for (int d = 0; d < 32; ++d) a[d] = A[h * 1024 + d * 32 + o];

    for (int r = 0; r < 32; ++r) {
        float s = 0.f;
        #pragma unroll
        for (int d = 0; d < 32; ++d) s = fmaf(Wsh[r][(h << 5) + d], a[d], s);
        Wdst[(chunk * 32 + r) * 256 + tid] = s;
    }
    if (chunk == 0) {
        float s = 0.f;
        #pragma unroll
        for (int d = 0; d < 32; ++d) s = fmaf(bsrc[(h << 5) + d], a[d], s);
        bdst[tid] = s;
    }
}

// =====================================================================
// fp32 GEMM: C[N,256] = X[N,256] @ W[256,256] + bias, optional epilogues.
// EPI 0: none; EPI 1: alpha-mix with `extra` (alpha=sigmoid(skipv[skipIdx]));
// EPI 2: tanh(acc + bias + extra) (RNN cell fuse).
// Block tile 64x64, 256 threads (16x16), 4x4 per-thread register tile, BK=32.
// grid = (ceil(N/64), 4)
// =====================================================================
template <typename OutT, int EPI>
__global__ __launch_bounds__(256) void gemm256(
    const float* __restrict__ X, const float* __restrict__ W,
    const float* __restrict__ Bias, OutT* __restrict__ C, int N,
    const float* __restrict__ extra, const float* __restrict__ skipv, int skipIdx)
{
    __shared__ float Xs[32][68];  // [k][m], padded
    __shared__ float Ws[32][68];  // [k][n], padded
    const int tid = threadIdx.x;
    const int tx = tid & 15, ty = tid >> 4;
    const int row0 = blockIdx.x * 64;
    const int col0 = blockIdx.y * 64;
    float acc[4][4] = {};

    for (int k0 = 0; k0 < 256; k0 += 32) {
        #pragma unroll
        for (int i = 0; i < 2; ++i) {  // X tile (transposed store)
            int s = tid * 2 + i;
            int r = s >> 3;
            int c4 = (s & 7) << 2;
            int row = row0 + r;
            float4 v = {0.f, 0.f, 0.f, 0.f};
            if (row < N) v = *reinterpret_cast<const float4*>(X + row * 256 + k0 + c4);
            Xs[c4 + 0][r] = v.x; Xs[c4 + 1][r] = v.y;
            Xs[c4 + 2][r] = v.z; Xs[c4 + 3][r] = v.w;
        }
        #pragma unroll
        for (int i = 0; i < 2; ++i) {  // W tile
            int s = tid * 2 + i;
            int kk = s >> 4;
            int c4 = (s & 15) << 2;
            float4 v = *reinterpret_cast<const float4*>(W + (k0 + kk) * 256 + col0 + c4);
            *reinterpret_cast<float4*>(&Ws[kk][c4]) = v;
        }
        __syncthreads();
        #pragma unroll
        for (int k = 0; k < 32; ++k) {
            float4 xv = *reinterpret_cast<const float4*>(&Xs[k][ty << 2]);
            float4 wv = *reinterpret_cast<const float4*>(&Ws[k][tx << 2]);
            float xa[4] = {xv.x, xv.y, xv.z, xv.w};
            float wa[4] = {wv.x, wv.y, wv.z, wv.w};
            #pragma unroll
            for (int i = 0; i < 4; ++i)
                #pragma unroll
                for (int jj = 0; jj < 4; ++jj)
                    acc[i][jj] = fmaf(xa[i], wa[jj], acc[i][jj]);
        }
        __syncthreads();
    }

    float alpha = 0.f;
    if (EPI == 1) alpha = 1.f / (1.f + __expf(-skipv[skipIdx]));
    #pragma unroll
    for (int i = 0; i < 4; ++i) {
        int row = row0 + (ty << 2) + i;
        if (row >= N) continue;
        #pragma unroll
        for (int jj = 0; jj < 4; ++jj) {
            int col = col0 + (tx << 2) + jj;
            float v = acc[i][jj] + Bias[col];
            if (EPI == 1) v = alpha * v + (1.f - alpha) * extra[row * 256 + col];
            if (EPI == 2) v = tanhf(v + extra[row * 256 + col]);
            C[row * 256 + col] = (OutT)v;
        }
    }
}

// =====================================================================
// Fused dual-relation message kernel (pull-based; dst[e] == e % n_dst).
// One block per dst node. 256 threads = 8 heads x 32 lanes.
// Online softmax per head over this dst's edges; relu; mean of 2 relations.
// =====================================================================
__global__ __launch_bounds__(256) void msg2(
    const float* __restrict__ q,
    const bf16* __restrict__ keyA, const bf16* __restrict__ valA,
    const int* __restrict__ srcA, const int nA,
    const bf16* __restrict__ keyB, const bf16* __restrict__ valB,
    const int* __restrict__ srcB, const int nB,
    const float* __restrict__ relPri, const int relA, const int relB,
    float* __restrict__ out, const int n_dst)
{
    const int j = blockIdx.x;
    const int tid = threadIdx.x;
    const int h = tid >> 5;
    __shared__ int sidx[128];
    const float qv = q[j * 256 + tid];

    float res[2];
    #pragma unroll
    for (int rr = 0; rr < 2; ++rr) {
        const bf16* key = rr ? keyB : keyA;
        const bf16* val = rr ? valB : valA;
        const int* srcp = rr ? srcB : srcA;
        const int ne = rr ? nB : nA;
        const float pri = relPri[(rr ? relB : relA) * 8 + h];

        for (int t = tid; t < ne; t += 256) sidx[t] = srcp[j + t * n_dst];
        __syncthreads();

        float m = -3.0e38f, s = 0.f, acc = 0.f;
        for (int t = 0; t < ne; ++t) {
            const int src = sidx[t];
            float p = qv * __bfloat162float(key[src * 256 + tid]);
            #pragma unroll
            for (int o = 16; o > 0; o >>= 1) p += __shfl_xor(p, o);
            const float att = p * pri * INV_SQRT_DK;
            const float mn = fmaxf(m, att);
            const float c = __expf(m - mn);
            const float e = __expf(att - mn);
            const float vv = __bfloat162float(val[src * 256 + tid]);
            s = s * c + e;
            acc = acc * c + e * vv;
            m = mn;
        }
        res[rr] = fmaxf(acc / s, 0.f);
        __syncthreads();  // before next relation reuses sidx
    }
    out[j * 256 + tid] = 0.5f * (res[0] + res[1]);
}

// =====================================================================
// in-place LayerNorm over rows of 256; one wave per row, 4 rows/block
// =====================================================================
__global__ __launch_bounds__(256) void ln_inplace(
    float* __restrict__ data, const float* __restrict__ g,
    const float* __restrict__ b, int nrows)
{
    const int wid = threadIdx.x >> 6, lane = threadIdx.x & 63;
    const int row = blockIdx.x * 4 + wid;
    if (row >= nrows) return;
    float4 x = *reinterpret_cast<float4*>(data + row * 256 + lane * 4);
    float s  = x.x + x.y + x.z + x.w;
    float q2 = x.x * x.x + x.y * x.y + x.z * x.z + x.w * x.w;
    #pragma unroll
    for (int o = 32; o > 0; o >>= 1) {
        s  += __shfl_xor(s, o);
        q2 += __shfl_xor(q2, o);
    }
    const float mu  = s * (1.f / 256.f);
    const float var = q2 * (1.f / 256.f) - mu * mu;
    const float r = rsqrtf(var + 1e-5f);
    const float4 gg = *reinterpret_cast<const float4*>(g + lane * 4);
    const float4 bb = *reinterpret_cast<const float4*>(b + lane * 4);
    x.x = (x.x - mu) * r * gg.x + bb.x;
    x.y = (x.y - mu) * r * gg.y + bb.y;
    x.z = (x.z - mu) * r * gg.z + bb.z;
    x.w = (x.w - mu) * r * gg.w + bb.w;
    *reinterpret_cast<float4*>(data + row * 256 + lane * 4) = x;
}

// =====================================================================
extern "C" void kernel_launch(void* const* d_in, const int* in_sizes, int n_in,
                              void* d_out, int out_size, void* d_ws, size_t ws_size,
                              hipStream_t stream)
{
    const float* feat_topic = (const float*)d_in[0];
    const float* feat_word  = (const float*)d_in[1];
    const float* feat_doc   = (const float*)d_in[2];
    const float* ht_prev    = (const float*)d_in[3];
    const float* Wk  = (const float*)d_in[4];
    const float* bk  = (const float*)d_in[5];
    const float* Wq  = (const float*)d_in[6];
    const float* bq  = (const float*)d_in[7];
    const float* Wv  = (const float*)d_in[8];
    const float* bv  = (const float*)d_in[9];
    const float* Wa  = (const float*)d_in[10];
    const float* ba  = (const float*)d_in[11];
    const float* ln_g = (const float*)d_in[12];
    const float* ln_b = (const float*)d_in[13];
    const float* skip = (const float*)d_in[14];
    const float* Wih  = (const float*)d_in[15];
    const float* Whh  = (const float*)d_in[16];
    const float* bih  = (const float*)d_in[17];
    const float* bhh  = (const float*)d_in[18];
    const float* rel_pri = (const float*)d_in[19];
    const float* rel_att = (const float*)d_in[20];
    const float* rel_msg = (const float*)d_in[21];
    const int* src_tt = (const int*)d_in[22];
    const int* src_wt = (const int*)d_in[24];
    const int* src_td = (const int*)d_in[26];
    const int* src_wd = (const int*)d_in[28];

    // ---- workspace layout ----
    float* foldW   = (float*)d_ws;                  // 8*65536
    float* foldb   = foldW + 8 * 65536;             // 2048
    float* q_t     = foldb + 2048;                  // 512000
    float* q_d     = q_t + 512000;                  // 5120000
    float* r2      = q_d + 5120000;                 // 512000 (ht_prev@Whh + bhh)
    float* t_topic = r2 + 512000;                   // 512000
    float* mixb    = t_topic + 512000;              // 512000
    float* t_doc   = mixb + 512000;                 // 5120000
    bf16* key_tt = (bf16*)(t_doc + 5120000);        // 512000 elems
    bf16* val_tt = key_tt + 512000;
    bf16* key_wt = val_tt + 512000;                 // 12800000
    bf16* val_wt = key_wt + 12800000;
    bf16* key_wd = val_wt + 12800000;
    bf16* val_wd = key_wd + 12800000;
    bf16* key_td = val_wd + 12800000;               // 512000
    bf16* val_td = key_td + 512000;

    float* out_topic = (float*)d_out;               // [2000,256]
    float* out_doc   = out_topic + NT * 256;        // [20000,256]

    const dim3 blk(256);
    auto grid_for = [](int n) { return dim3((n + 63) / 64, 4); };

    // 1. fold relation matrices into projection weights
    fold_kernel<<<dim3(64), blk, 0, stream>>>(Wk, bk, Wv, bv, rel_att, rel_msg, foldW, foldb);

    // 2. projections (phase-1 independent batch)
    gemm256<float, 0><<<grid_for(NT), blk, 0, stream>>>(
        feat_topic, Wq + 0 * 65536, bq + 0 * 256, q_t, NT, nullptr, nullptr, 0);
    gemm256<float, 0><<<grid_for(ND), blk, 0, stream>>>(
        feat_doc, Wq + 2 * 65536, bq + 2 * 256, q_d, ND, nullptr, nullptr, 0);
    gemm256<bf16, 0><<<grid_for(NT), blk, 0, stream>>>(
        feat_topic, foldW + 0 * 65536, foldb + 0 * 256, key_tt, NT, nullptr, nullptr, 0);
    gemm256<bf16, 0><<<grid_for(NT), blk, 0, stream>>>(
        feat_topic, foldW + 1 * 65536, foldb + 1 * 256, val_tt, NT, nullptr, nullptr, 0);
    gemm256<bf16, 0><<<grid_for(NW), blk, 0, stream>>>(
        feat_word, foldW + 2 * 65536, foldb + 2 * 256, key_wt, NW, nullptr, nullptr, 0);
    gemm256<bf16, 0><<<grid_for(NW), blk, 0, stream>>>(
        feat_word, foldW + 3 * 65536, foldb + 3 * 256, val_wt, NW, nullptr, nullptr, 0);
    gemm256<bf16, 0><<<grid_for(NW), blk, 0, stream>>>(
        feat_word, foldW + 6 * 65536, foldb + 6 * 256, key_wd, NW, nullptr, nullptr, 0);
    gemm256<bf16, 0><<<grid_for(NW), blk, 0, stream>>>(
        feat_word, foldW + 7 * 65536, foldb + 7 * 256, val_wd, NW, nullptr, nullptr, 0);
    gemm256<float, 0><<<grid_for(NT), blk, 0, stream>>>(
        ht_prev, Whh, bhh, r2, NT, nullptr, nullptr, 0);

    // 3. messages into topic (tt: 64 edges/dst, wt: 128 edges/dst)
    msg2<<<dim3(NT), blk, 0, stream>>>(
        q_t, key_tt, val_tt, src_tt, E_TT / NT,
        key_wt, val_wt, src_wt, E_WT / NT,
        rel_pri, 0, 1, t_topic, NT);

    // 4. topic update: mix -> RNN tanh -> LN (in-place on d_out)
    gemm256<float, 1><<<grid_for(NT), blk, 0, stream>>>(
        t_topic, Wa + 0 * 65536, ba + 0 * 256, mixb, NT, feat_topic, skip, 0);
    gemm256<float, 2><<<grid_for(NT), blk, 0, stream>>>(
        mixb, Wih, bih, out_topic, NT, r2, nullptr, 0);
    ln_inplace<<<dim3((NT + 3) / 4), blk, 0, stream>>>(out_topic, ln_g + 0, ln_b + 0, NT);

    // 5. phase-2 topic projections from updated topic_out
    gemm256<bf16, 0><<<grid_for(NT), blk, 0, stream>>>(
        out_topic, foldW + 4 * 65536, foldb + 4 * 256, key_td, NT, nullptr, nullptr, 0);
    gemm256<bf16, 0><<<grid_for(NT), blk, 0, stream>>>(
        out_topic, foldW + 5 * 65536, foldb + 5 * 256, val_td, NT, nullptr, nullptr, 0);

    // 6. messages into doc (td: 16 edges/dst, wd: 16 edges/dst)
    msg2<<<dim3(ND), blk, 0, stream>>>(
        q_d, key_td, val_td, src_td, E_TD / ND,
        key_wd, val_wd, src_wd, E_WD / ND,
        rel_pri, 2, 3, t_doc, ND);

    // 7. doc update: mix (fused into GEMM epilogue, writes d_out) -> LN in-place
    gemm256<float, 1><<<grid_for(ND), blk, 0, stream>>>(
        t_doc, Wa + 1 * 65536, ba + 1 * 256, out_doc, ND, feat_doc, skip, 1);
    ln_inplace<<<dim3((ND + 3) / 4), blk, 0, stream>>>(out_doc, ln_g + 256, ln_b + 256, ND);
}

// Round 2
// 603.644 us; speedup vs baseline: 1.6698x; 1.6698x over previous
//
#include <hip/hip_runtime.h>
#include <hip/hip_bf16.h>

typedef __attribute__((ext_vector_type(8))) short bf16x8;
typedef __attribute__((ext_vector_type(4))) float f32x4;

constexpr int NT = 2000, NW = 50000, ND = 20000;
constexpr float INV_SQRT_DK = 0.17677669529663687f;  // 1/sqrt(32)

__device__ inline float bfu(unsigned short u) {
    return __uint_as_float(((unsigned int)u) << 16);
}
__device__ inline short f2bf(float x) {
    __hip_bfloat16 h = __float2bfloat16(x);
    short s; __builtin_memcpy(&s, &h, 2); return s;
}
__device__ inline void cstore(float* p, float v) { *p = v; }
__device__ inline void cstore(short* p, float v) { *p = f2bf(v); }

// =====================================================================
// fold: per-relation head transforms folded into projection weights,
// written TRANSPOSED bf16 ([n][k]) into the packed B matrices.
// f = rel*2 + isV; rel 0=tt,1=wt,2=td,3=wd.
// =====================================================================
__global__ __launch_bounds__(256) void fold_kernel(
    const float* __restrict__ Wk, const float* __restrict__ bk,
    const float* __restrict__ Wv, const float* __restrict__ bv,
    const float* __restrict__ rel_att, const float* __restrict__ rel_msg,
    short* __restrict__ B_t1, short* __restrict__ B_w, short* __restrict__ B_t2,
    float* __restrict__ bias_t1, float* __restrict__ bias_w, float* __restrict__ bias_t2)
{
    const int f = blockIdx.x >> 3, chunk = blockIdx.x & 7;
    const int rel = f >> 1, isV = f & 1;
    const int ntype = (rel == 1 || rel == 3) ? 1 : 0;
    const float* Wsrc = (isV ? Wv : Wk) + ntype * 65536;
    const float* bsrc = (isV ? bv : bk) + ntype * 256;
    const float* A    = (isV ? rel_msg : rel_att) + rel * 8192;  // [8][32][32]
    short* wdst; float* bdst;
    switch (f) {
        case 0: wdst = B_t1 + 65536;     bdst = bias_t1 + 256; break;  // K tt
        case 1: wdst = B_t1 + 2 * 65536; bdst = bias_t1 + 512; break;  // V tt
        case 2: wdst = B_w;              bdst = bias_w;        break;  // K wt
        case 3: wdst = B_w + 65536;      bdst = bias_w + 256;  break;  // V wt
        case 4: wdst = B_t2;             bdst = bias_t2;       break;  // K td
        case 5: wdst = B_t2 + 65536;     bdst = bias_t2 + 256; break;  // V td
        case 6: wdst = B_w + 2 * 65536;  bdst = bias_w + 512;  break;  // K wd
        default: wdst = B_w + 3 * 65536; bdst = bias_w + 768;  break;  // V wd
    }
    __shared__ float Wsh[32][256];
    const int tid = threadIdx.x;
    for (int i = 0; i < 32; ++i)
        Wsh[i][tid] = Wsrc[(chunk * 32 + i) * 256 + tid];
    __syncthreads();
    const int h = tid >> 5, o = tid & 31;
    float a[32];
    #pragma unroll
    for (int d = 0; d < 32; ++d) a[d] = A[h * 1024 + d * 32 + o];
    short tmp[32];
    #pragma unroll
    for (int r = 0; r < 32; ++r) {
        float s = 0.f;
        #pragma unroll
        for (int d = 0; d < 32; ++d) s = fmaf(Wsh[r][(h << 5) + d], a[d], s);
        tmp[r] = f2bf(s);
    }
    // transposed: wdst[col=tid][k = chunk*32 + r]
    short* wp = wdst + tid * 256 + chunk * 32;
    #pragma unroll
    for (int r8 = 0; r8 < 4; ++r8) {
        bf16x8 v;
        #pragma unroll
        for (int t = 0; t < 8; ++t) v[t] = tmp[r8 * 8 + t];
        *reinterpret_cast<bf16x8*>(wp + r8 * 8) = v;
    }
    if (chunk == 0) {
        float s = 0.f;
        #pragma unroll
        for (int d = 0; d < 32; ++d) s = fmaf(bsrc[(h << 5) + d], a[d], s);
        bdst[tid] = s;
    }
}

// transpose-convert 6 plain 256x256 weights to [n][k] bf16
struct TransP { const float* s[6]; short* d[6]; };
__global__ __launch_bounds__(256) void wtrans6(TransP p) {
    const int m = blockIdx.y, n = blockIdx.x, k = threadIdx.x;
    p.d[m][n * 256 + k] = f2bf(p.s[m][k * 256 + n]);
}

__global__ void copy_bias(const float* __restrict__ s, float* __restrict__ d) {
    d[threadIdx.x] = s[threadIdx.x];
}

// =====================================================================
// MFMA GEMM: C[M][ldc] = X[M][256] @ Wt^T + bias (Wt stored [NC][256] bf16)
// 128x128 block tile, 4 waves (2x2), each wave 4x4 frags of 16x16x32 bf16.
// EPI 0: none; 1: sigmoid-skip mix with extra; 2: tanh(acc+bias+extra).
// =====================================================================
template <bool XF32, typename OutT, int EPI>
__global__ __launch_bounds__(256) void gemm_mfma(
    const void* __restrict__ Xv, const short* __restrict__ Wt,
    const float* __restrict__ bias, OutT* __restrict__ C,
    int M, int ldc, const float* __restrict__ extra,
    const float* __restrict__ skipv, int skipIdx)
{
    const int tid = threadIdx.x;
    const int wave = tid >> 6, lane = tid & 63;
    const int wm = wave >> 1, wn = wave & 1;
    const int r = lane & 15, kb = lane >> 4;
    const int row0 = blockIdx.x * 128 + wm * 64;
    const int col0 = blockIdx.y * 128 + wn * 64;
    f32x4 acc[4][4] = {};

    for (int k0 = 0; k0 < 256; k0 += 32) {
        bf16x8 af[4], bw[4];
        #pragma unroll
        for (int i = 0; i < 4; ++i) {
            int row = row0 + i * 16 + r;
            row = row < M ? row : M - 1;
            if constexpr (XF32) {
                const float* xp = (const float*)Xv + row * 256 + k0 + kb * 8;
                float4 x0 = *reinterpret_cast<const float4*>(xp);
                float4 x1 = *reinterpret_cast<const float4*>(xp + 4);
                bf16x8 v;
                v[0] = f2bf(x0.x); v[1] = f2bf(x0.y); v[2] = f2bf(x0.z); v[3] = f2bf(x0.w);
                v[4] = f2bf(x1.x); v[5] = f2bf(x1.y); v[6] = f2bf(x1.z); v[7] = f2bf(x1.w);
                af[i] = v;
            } else {
                af[i] = *reinterpret_cast<const bf16x8*>((const short*)Xv + row * 256 + k0 + kb * 8);
            }
            const int col = col0 + i * 16 + r;
            bw[i] = *reinterpret_cast<const bf16x8*>(Wt + col * 256 + k0 + kb * 8);
        }
        #pragma unroll
        for (int i = 0; i < 4; ++i)
            #pragma unroll
            for (int j = 0; j < 4; ++j)
                acc[i][j] = __builtin_amdgcn_mfma_f32_16x16x32_bf16(af[i], bw[j], acc[i][j], 0, 0, 0);
    }

    float alpha = 0.f;
    if (EPI == 1) alpha = 1.f / (1.f + __expf(-skipv[skipIdx]));
    #pragma unroll
    for (int i = 0; i < 4; ++i) {
        #pragma unroll
        for (int j = 0; j < 4; ++j) {
            const int col = col0 + j * 16 + r;
            const float bc = bias[col];
            #pragma unroll
            for (int t = 0; t < 4; ++t) {
                const int rrow = row0 + i * 16 + kb * 4 + t;
                if (rrow < M) {
                    float v = acc[i][j][t] + bc;
                    if (EPI == 1) v = alpha * v + (1.f - alpha) * extra[rrow * 256 + col];
                    if (EPI == 2) v = tanhf(v + extra[rrow * 256 + col]);
                    cstore(C + rrow * ldc + col, v);
                }
            }
        }
    }
}

// =====================================================================
// Parallel dual-relation message kernel. One block per dst.
// Phase 1: all (edge,head) scores in parallel. Phase 2: per-head 32-lane
// shuffle softmax. Phase 3: coalesced weighted accumulation.
// =====================================================================
__global__ __launch_bounds__(256) void msg_k(
    const short* __restrict__ q, int ldq,
    const short* __restrict__ keyA, const short* __restrict__ valA, int ldA,
    const int* __restrict__ srcA, int neA,
    const short* __restrict__ keyB, const short* __restrict__ valB, int ldB,
    const int* __restrict__ srcB, int neB,
    const float* __restrict__ relPri, int relA, int relB,
    short* __restrict__ out, int n_dst)
{
    const int j = blockIdx.x, tid = threadIdx.x;
    __shared__ float qsh[256];
    __shared__ int sidx[192];
    __shared__ float sc[192 * 9];
    __shared__ float ssum[2][8];

    qsh[tid] = bfu((unsigned short)q[j * ldq + tid]);
    for (int t = tid; t < neA; t += 256) sidx[t] = srcA[j + t * n_dst];
    for (int t = tid; t < neB; t += 256) sidx[neA + t] = srcB[j + t * n_dst];
    __syncthreads();

    const int netot = neA + neB;
    for (int p = tid; p < netot * 8; p += 256) {
        const int eg = p >> 3, h = p & 7;
        const bool isB = eg >= neA;
        const short* key = isB ? keyB : keyA;
        const int ld = isB ? ldB : ldA;
        const int src = sidx[eg];
        const unsigned short* kp = (const unsigned short*)(key + src * ld + h * 32);
        const float* qh = qsh + h * 32;
        float dot = 0.f;
        #pragma unroll
        for (int d = 0; d < 32; d += 4) {
            ushort4 kv = *reinterpret_cast<const ushort4*>(kp + d);
            dot += qh[d] * bfu(kv.x) + qh[d + 1] * bfu(kv.y)
                 + qh[d + 2] * bfu(kv.z) + qh[d + 3] * bfu(kv.w);
        }
        const float pri = relPri[(isB ? relB : relA) * 8 + h];
        sc[eg * 9 + h] = dot * pri * INV_SQRT_DK;
    }
    __syncthreads();

    {   // per-head softmax (8 groups of 32 lanes)
        const int g = tid >> 5, l = tid & 31;
        #pragma unroll
        for (int rr = 0; rr < 2; ++rr) {
            const int ne = rr ? neB : neA, off = rr ? neA : 0;
            float m = -3.0e38f;
            for (int e = l; e < ne; e += 32) m = fmaxf(m, sc[(off + e) * 9 + g]);
            #pragma unroll
            for (int o = 16; o > 0; o >>= 1) m = fmaxf(m, __shfl_xor(m, o));
            float s = 0.f;
            for (int e = l; e < ne; e += 32) {
                float ex = __expf(sc[(off + e) * 9 + g] - m);
                sc[(off + e) * 9 + g] = ex;
                s += ex;
            }
            #pragma unroll
            for (int o = 16; o > 0; o >>= 1) s += __shfl_xor(s, o);
            if (l == 0) ssum[rr][g] = s;
        }
    }
    __syncthreads();

    const int h = tid >> 5;
    float accA = 0.f, accB = 0.f;
    #pragma unroll 4
    for (int e = 0; e < neA; ++e)
        accA += sc[e * 9 + h] * bfu((unsigned short)valA[sidx[e] * ldA + tid]);
    #pragma unroll 4
    for (int e = 0; e < neB; ++e)
        accB += sc[(neA + e) * 9 + h] * bfu((unsigned short)valB[sidx[neA + e] * ldB + tid]);
    const float rA = fmaxf(accA / ssum[0][h], 0.f);
    const float rB = fmaxf(accB / ssum[1][h], 0.f);
    out[j * 256 + tid] = f2bf(0.5f * (rA + rB));
}

// =====================================================================
// in-place LayerNorm; optionally also writes a bf16 copy
// =====================================================================
template <bool WB>
__global__ __launch_bounds__(256) void ln_k(
    float* __restrict__ data, const float* __restrict__ g,
    const float* __restrict__ b, int nrows, short* __restrict__ bfout)
{
    const int wid = threadIdx.x >> 6, lane = threadIdx.x & 63;
    const int row = blockIdx.x * 4 + wid;
    if (row >= nrows) return;
    float4 x = *reinterpret_cast<float4*>(data + row * 256 + lane * 4);
    float s  = x.x + x.y + x.z + x.w;
    float q2 = x.x * x.x + x.y * x.y + x.z * x.z + x.w * x.w;
    #pragma unroll
    for (int o = 32; o > 0; o >>= 1) { s += __shfl_xor(s, o); q2 += __shfl_xor(q2, o); }
    const float mu  = s * (1.f / 256.f);
    const float var = q2 * (1.f / 256.f) - mu * mu;
    const float rr = rsqrtf(var + 1e-5f);
    const float4 gg = *reinterpret_cast<const float4*>(g + lane * 4);
    const float4 bb = *reinterpret_cast<const float4*>(b + lane * 4);
    x.x = (x.x - mu) * rr * gg.x + bb.x;
    x.y = (x.y - mu) * rr * gg.y + bb.y;
    x.z = (x.z - mu) * rr * gg.z + bb.z;
    x.w = (x.w - mu) * rr * gg.w + bb.w;
    *reinterpret_cast<float4*>(data + row * 256 + lane * 4) = x;
    if (WB) {
        ushort4 u;
        u.x = (unsigned short)f2bf(x.x); u.y = (unsigned short)f2bf(x.y);
        u.z = (unsigned short)f2bf(x.z); u.w = (unsigned short)f2bf(x.w);
        *reinterpret_cast<ushort4*>((unsigned short*)bfout + row * 256 + lane * 4) = u;
    }
}

// =====================================================================
extern "C" void kernel_launch(void* const* d_in, const int* in_sizes, int n_in,
                              void* d_out, int out_size, void* d_ws, size_t ws_size,
                              hipStream_t stream)
{
    const float* feat_topic = (const float*)d_in[0];
    const float* feat_word  = (const float*)d_in[1];
    const float* feat_doc   = (const float*)d_in[2];
    const float* ht_prev    = (const float*)d_in[3];
    const float* Wk  = (const float*)d_in[4];
    const float* bk  = (const float*)d_in[5];
    const float* Wq  = (const float*)d_in[6];
    const float* bq  = (const float*)d_in[7];
    const float* Wv  = (const float*)d_in[8];
    const float* bv  = (const float*)d_in[9];
    const float* Wa  = (const float*)d_in[10];
    const float* ba  = (const float*)d_in[11];
    const float* ln_g = (const float*)d_in[12];
    const float* ln_b = (const float*)d_in[13];
    const float* skip = (const float*)d_in[14];
    const float* Wih  = (const float*)d_in[15];
    const float* Whh  = (const float*)d_in[16];
    const float* bih  = (const float*)d_in[17];
    const float* bhh  = (const float*)d_in[18];
    const float* rel_pri = (const float*)d_in[19];
    const float* rel_att = (const float*)d_in[20];
    const float* rel_msg = (const float*)d_in[21];
    const int* src_tt = (const int*)d_in[22];
    const int* src_wt = (const int*)d_in[24];
    const int* src_td = (const int*)d_in[26];
    const int* src_wd = (const int*)d_in[28];

    // ---- workspace layout (shorts first, then floats) ----
    short* B_t1 = (short*)d_ws;                 // 768*256
    short* B_w  = B_t1 + 196608;                // 1024*256
    short* B_t2 = B_w + 262144;                 // 512*256
    short* Wq2t = B_t2 + 131072;                // 5 x 256*256
    short* Whht = Wq2t + 65536;
    short* Wa0t = Whht + 65536;
    short* Wiht = Wa0t + 65536;
    short* Wa1t = Wiht + 65536;
    short* out1 = Wa1t + 65536;                 // 2000*768   (q_t | key_tt | val_tt)
    short* out2 = out1 + 1536000;               // 50000*1024 (Kwt | Vwt | Kwd | Vwd)
    short* out3 = out2 + 51200000;              // 2000*512   (Ktd | Vtd)
    short* qd   = out3 + 1024000;               // 20000*256
    short* ttop = qd + 5120000;                 // 2000*256
    short* mixb = ttop + 512000;                // 2000*256
    short* tdoc = mixb + 512000;                // 20000*256
    short* xt2  = tdoc + 5120000;               // 2000*256
    float* bias_t1 = (float*)(xt2 + 512000);    // 768
    float* bias_w  = bias_t1 + 768;             // 1024
    float* bias_t2 = bias_w + 1024;             // 512
    float* r2      = bias_t2 + 512;             // 2000*256 fp32

    float* out_topic = (float*)d_out;
    float* out_doc   = out_topic + NT * 256;

    // ---- weight prep ----
    fold_kernel<<<dim3(64), 256, 0, stream>>>(Wk, bk, Wv, bv, rel_att, rel_msg,
                                              B_t1, B_w, B_t2, bias_t1, bias_w, bias_t2);
    TransP tp;
    tp.s[0] = Wq;            tp.d[0] = B_t1;   // Wq[topic] -> B_t1 rows 0..255
    tp.s[1] = Wq + 131072;   tp.d[1] = Wq2t;   // Wq[doc]
    tp.s[2] = Whh;           tp.d[2] = Whht;
    tp.s[3] = Wih;           tp.d[3] = Wiht;
    tp.s[4] = Wa;            tp.d[4] = Wa0t;
    tp.s[5] = Wa + 65536;    tp.d[5] = Wa1t;
    wtrans6<<<dim3(256, 6), 256, 0, stream>>>(tp);
    copy_bias<<<dim3(1), 256, 0, stream>>>(bq, bias_t1);

    // ---- phase-1 projections ----
    gemm_mfma<true, short, 0><<<dim3(16, 6), 256, 0, stream>>>(
        feat_topic, B_t1, bias_t1, out1, NT, 768, nullptr, nullptr, 0);
    gemm_mfma<true, short, 0><<<dim3(391, 8), 256, 0, stream>>>(
        feat_word, B_w, bias_w, out2, NW, 1024, nullptr, nullptr, 0);
    gemm_mfma<true, short, 0><<<dim3(157, 2), 256, 0, stream>>>(
        feat_doc, Wq2t, bq + 512, qd, ND, 256, nullptr, nullptr, 0);
    gemm_mfma<true, float, 0><<<dim3(16, 2), 256, 0, stream>>>(
        ht_prev, Whht, bhh, r2, NT, 256, nullptr, nullptr, 0);

    // ---- messages into topic (tt:64/dst, wt:128/dst) ----
    msg_k<<<dim3(NT), 256, 0, stream>>>(
        out1, 768,
        out1 + 256, out1 + 512, 768, src_tt, 64,
        out2, out2 + 256, 1024, src_wt, 128,
        rel_pri, 0, 1, ttop, NT);

    // ---- topic update: mix -> RNN tanh -> LN ----
    gemm_mfma<false, short, 1><<<dim3(16, 2), 256, 0, stream>>>(
        ttop, Wa0t, ba, mixb, NT, 256, feat_topic, skip, 0);
    gemm_mfma<false, float, 2><<<dim3(16, 2), 256, 0, stream>>>(
        mixb, Wiht, bih, out_topic, NT, 256, r2, nullptr, 0);
    ln_k<true><<<dim3(500), 256, 0, stream>>>(out_topic, ln_g, ln_b, NT, xt2);

    // ---- phase-2 topic projections ----
    gemm_mfma<false, short, 0><<<dim3(16, 4), 256, 0, stream>>>(
        xt2, B_t2, bias_t2, out3, NT, 512, nullptr, nullptr, 0);

    // ---- messages into doc (td:16/dst, wd:16/dst) ----
    msg_k<<<dim3(ND), 256, 0, stream>>>(
        qd, 256,
        out3, out3 + 256, 512, src_td, 16,
        out2 + 512, out2 + 768, 1024, src_wd, 16,
        rel_pri, 2, 3, tdoc, ND);

    // ---- doc update: mix -> LN ----
    gemm_mfma<false, float, 1><<<dim3(157, 2), 256, 0, stream>>>(
        tdoc, Wa1t, ba + 256, out_doc, ND, 256, feat_doc, skip, 1);
    ln_k<false><<<dim3(5000), 256, 0, stream>>>(out_doc, ln_g + 256, ln_b + 256, ND, nullptr);
}

// Round 3
// 477.231 us; speedup vs baseline: 2.1121x; 1.2649x over previous
//
#include <hip/hip_runtime.h>
#include <hip/hip_bf16.h>

typedef __attribute__((ext_vector_type(8))) short bf16x8;
typedef __attribute__((ext_vector_type(4))) float f32x4;

constexpr int NT = 2000, NW = 50000, ND = 20000;
constexpr float INV_SQRT_DK = 0.17677669529663687f;  // 1/sqrt(32)

__device__ inline float bfu(unsigned short u) {
    return __uint_as_float(((unsigned int)u) << 16);
}
__device__ inline short f2bf(float x) {
    __hip_bfloat16 h = __float2bfloat16(x);
    short s; __builtin_memcpy(&s, &h, 2); return s;
}
__device__ inline void cstore(float* p, float v) { *p = v; }
__device__ inline void cstore(short* p, float v) { *p = f2bf(v); }

__device__ inline void gload16(const short* g, short* l) {
    __builtin_amdgcn_global_load_lds(
        (const __attribute__((address_space(1))) void*)g,
        (__attribute__((address_space(3))) void*)l, 16, 0, 0);
}

// =====================================================================
// fold: per-relation head transforms folded into projection weights,
// written TRANSPOSED bf16 ([n][k]) into the packed B matrices.
// =====================================================================
__global__ __launch_bounds__(256) void fold_kernel(
    const float* __restrict__ Wk, const float* __restrict__ bk,
    const float* __restrict__ Wv, const float* __restrict__ bv,
    const float* __restrict__ rel_att, const float* __restrict__ rel_msg,
    short* __restrict__ B_t1, short* __restrict__ B_w, short* __restrict__ B_t2,
    float* __restrict__ bias_t1, float* __restrict__ bias_w, float* __restrict__ bias_t2)
{
    const int f = blockIdx.x >> 3, chunk = blockIdx.x & 7;
    const int rel = f >> 1, isV = f & 1;
    const int ntype = (rel == 1 || rel == 3) ? 1 : 0;
    const float* Wsrc = (isV ? Wv : Wk) + ntype * 65536;
    const float* bsrc = (isV ? bv : bk) + ntype * 256;
    const float* A    = (isV ? rel_msg : rel_att) + rel * 8192;  // [8][32][32]
    short* wdst; float* bdst;
    switch (f) {
        case 0: wdst = B_t1 + 65536;     bdst = bias_t1 + 256; break;  // K tt
        case 1: wdst = B_t1 + 2 * 65536; bdst = bias_t1 + 512; break;  // V tt
        case 2: wdst = B_w;              bdst = bias_w;        break;  // K wt
        case 3: wdst = B_w + 65536;      bdst = bias_w + 256;  break;  // V wt
        case 4: wdst = B_t2;             bdst = bias_t2;       break;  // K td
        case 5: wdst = B_t2 + 65536;     bdst = bias_t2 + 256; break;  // V td
        case 6: wdst = B_w + 2 * 65536;  bdst = bias_w + 512;  break;  // K wd
        default: wdst = B_w + 3 * 65536; bdst = bias_w + 768;  break;  // V wd
    }
    __shared__ float Wsh[32][256];
    const int tid = threadIdx.x;
    for (int i = 0; i < 32; ++i)
        Wsh[i][tid] = Wsrc[(chunk * 32 + i) * 256 + tid];
    __syncthreads();
    const int h = tid >> 5, o = tid & 31;
    float a[32];
    #pragma unroll
    for (int d = 0; d < 32; ++d) a[d] = A[h * 1024 + d * 32 + o];
    short tmp[32];
    #pragma unroll
    for (int r = 0; r < 32; ++r) {
        float s = 0.f;
        #pragma unroll
        for (int d = 0; d < 32; ++d) s = fmaf(Wsh[r][(h << 5) + d], a[d], s);
        tmp[r] = f2bf(s);
    }
    short* wp = wdst + tid * 256 + chunk * 32;
    #pragma unroll
    for (int r8 = 0; r8 < 4; ++r8) {
        bf16x8 v;
        #pragma unroll
        for (int t = 0; t < 8; ++t) v[t] = tmp[r8 * 8 + t];
        *reinterpret_cast<bf16x8*>(wp + r8 * 8) = v;
    }
    if (chunk == 0) {
        float s = 0.f;
        #pragma unroll
        for (int d = 0; d < 32; ++d) s = fmaf(bsrc[(h << 5) + d], a[d], s);
        bdst[tid] = s;
    }
}

struct TransP { const float* s[6]; short* d[6]; };
__global__ __launch_bounds__(256) void wtrans6(TransP p) {
    const int m = blockIdx.y, n = blockIdx.x, k = threadIdx.x;
    p.d[m][n * 256 + k] = f2bf(p.s[m][k * 256 + n]);
}

__global__ void copy_bias(const float* __restrict__ s, float* __restrict__ d) {
    d[threadIdx.x] = s[threadIdx.x];
}

// =====================================================================
// LDS-staged MFMA GEMM (m97 structure): C[M][ldc] = X[M][256] @ Wt^T + bias
// 128x128 block tile, BK=64, single-buffered LDS with st-16x32-style XOR
// swizzle. B (and bf16 A) staged via global_load_lds w=16 with pre-swizzled
// source col; fp32 A reg-staged with fused cvt + swizzled ds_write_b128.
// 4 waves (2x2), each 4x4 frags of mfma_f32_16x16x32_bf16.
// EPI 0: none; 1: sigmoid-skip mix; 2: tanh(acc+bias+extra).
// =====================================================================
template <bool XF32, typename OutT, int EPI>
__global__ __launch_bounds__(256) void gemm_lds(
    const void* __restrict__ Xv, const short* __restrict__ Wt,
    const float* __restrict__ bias, OutT* __restrict__ C,
    int M, int ldc, const float* __restrict__ extra,
    const float* __restrict__ skipv, int skipIdx)
{
    __shared__ short As[128 * 64];
    __shared__ short Bs[128 * 64];
    const int tid = threadIdx.x;
    const int wave = tid >> 6, lane = tid & 63;
    const int wm = wave >> 1, wn = wave & 1;
    const int r = lane & 15, kb = lane >> 4;
    const int col0 = blockIdx.x * 128;
    const int row0 = blockIdx.y * 128;

    // staging geometry: instr q covers tile rows wave*32+q*8 .. +8
    const int l8 = lane >> 3;                // 0..7 (row within 8-row chunk)
    const int c8 = lane & 7;                 // logical col8 for reg-stage
    const int swz8 = c8 ^ l8;                // pre-swizzled col8 for linear-dest staging
    f32x4 acc[4][4] = {};

    for (int k0 = 0; k0 < 256; k0 += 64) {
        if (k0) __syncthreads();
        // ---- stage A ----
        if constexpr (XF32) {
            #pragma unroll
            for (int q = 0; q < 4; ++q) {
                const int rl = wave * 32 + q * 8 + l8;
                const int grow = min(row0 + rl, M - 1);
                const float* xp = (const float*)Xv + grow * 256 + k0 + c8 * 8;
                const float4 x0 = *reinterpret_cast<const float4*>(xp);
                const float4 x1 = *reinterpret_cast<const float4*>(xp + 4);
                bf16x8 v;
                v[0] = f2bf(x0.x); v[1] = f2bf(x0.y); v[2] = f2bf(x0.z); v[3] = f2bf(x0.w);
                v[4] = f2bf(x1.x); v[5] = f2bf(x1.y); v[6] = f2bf(x1.z); v[7] = f2bf(x1.w);
                *reinterpret_cast<bf16x8*>(As + rl * 64 + swz8 * 8) = v;  // phys = linear ^ ((row&7)<<4)
            }
        } else {
            #pragma unroll
            for (int q = 0; q < 4; ++q) {
                const int rl = wave * 32 + q * 8 + l8;
                const int grow = min(row0 + rl, M - 1);
                gload16((const short*)Xv + grow * 256 + k0 + swz8 * 8,
                        As + (wave * 32 + q * 8) * 64);
            }
        }
        // ---- stage B ----
        #pragma unroll
        for (int q = 0; q < 4; ++q) {
            const int cl = wave * 32 + q * 8 + l8;
            gload16(Wt + (col0 + cl) * 256 + k0 + swz8 * 8,
                    Bs + (wave * 32 + q * 8) * 64);
        }
        __syncthreads();
        // ---- compute ----
        #pragma unroll
        for (int s = 0; s < 2; ++s) {
            const int csw = ((kb + 4 * s) ^ (r & 7)) * 8;
            bf16x8 af[4], bw[4];
            #pragma unroll
            for (int i = 0; i < 4; ++i) {
                af[i] = *reinterpret_cast<const bf16x8*>(As + (wm * 64 + i * 16 + r) * 64 + csw);
                bw[i] = *reinterpret_cast<const bf16x8*>(Bs + (wn * 64 + i * 16 + r) * 64 + csw);
            }
            #pragma unroll
            for (int i = 0; i < 4; ++i)
                #pragma unroll
                for (int j = 0; j < 4; ++j)
                    acc[i][j] = __builtin_amdgcn_mfma_f32_16x16x32_bf16(af[i], bw[j], acc[i][j], 0, 0, 0);
        }
    }

    float alpha = 0.f;
    if (EPI == 1) alpha = 1.f / (1.f + __expf(-skipv[skipIdx]));
    #pragma unroll
    for (int i = 0; i < 4; ++i) {
        #pragma unroll
        for (int j = 0; j < 4; ++j) {
            const int col = col0 + wn * 64 + j * 16 + r;
            const float bc = bias[col];
            #pragma unroll
            for (int t = 0; t < 4; ++t) {
                const int rrow = row0 + wm * 64 + i * 16 + kb * 4 + t;
                if (rrow < M) {
                    float v = acc[i][j][t] + bc;
                    if (EPI == 1) v = alpha * v + (1.f - alpha) * extra[rrow * 256 + col];
                    if (EPI == 2) v = tanhf(v + extra[rrow * 256 + col]);
                    cstore(C + rrow * ldc + col, v);
                }
            }
        }
    }
}

// =====================================================================
// Parallel dual-relation message kernel. One block per dst.
// =====================================================================
__global__ __launch_bounds__(256) void msg_k(
    const short* __restrict__ q, int ldq,
    const short* __restrict__ keyA, const short* __restrict__ valA, int ldA,
    const int* __restrict__ srcA, int neA,
    const short* __restrict__ keyB, const short* __restrict__ valB, int ldB,
    const int* __restrict__ srcB, int neB,
    const float* __restrict__ relPri, int relA, int relB,
    short* __restrict__ out, int n_dst)
{
    const int j = blockIdx.x, tid = threadIdx.x;
    __shared__ float qsh[256];
    __shared__ int sidx[192];
    __shared__ float sc[192 * 9];
    __shared__ float ssum[2][8];

    qsh[tid] = bfu((unsigned short)q[j * ldq + tid]);
    for (int t = tid; t < neA; t += 256) sidx[t] = srcA[j + t * n_dst];
    for (int t = tid; t < neB; t += 256) sidx[neA + t] = srcB[j + t * n_dst];
    __syncthreads();

    const int netot = neA + neB;
    for (int p = tid; p < netot * 8; p += 256) {
        const int eg = p >> 3, h = p & 7;
        const bool isB = eg >= neA;
        const short* key = isB ? keyB : keyA;
        const int ld = isB ? ldB : ldA;
        const int src = sidx[eg];
        const unsigned short* kp = (const unsigned short*)(key + src * ld + h * 32);
        const float* qh = qsh + h * 32;
        float dot = 0.f;
        #pragma unroll
        for (int d = 0; d < 32; d += 4) {
            ushort4 kv = *reinterpret_cast<const ushort4*>(kp + d);
            dot += qh[d] * bfu(kv.x) + qh[d + 1] * bfu(kv.y)
                 + qh[d + 2] * bfu(kv.z) + qh[d + 3] * bfu(kv.w);
        }
        const float pri = relPri[(isB ? relB : relA) * 8 + h];
        sc[eg * 9 + h] = dot * pri * INV_SQRT_DK;
    }
    __syncthreads();

    {   // per-head softmax (8 groups of 32 lanes)
        const int g = tid >> 5, l = tid & 31;
        #pragma unroll
        for (int rr = 0; rr < 2; ++rr) {
            const int ne = rr ? neB : neA, off = rr ? neA : 0;
            float m = -3.0e38f;
            for (int e = l; e < ne; e += 32) m = fmaxf(m, sc[(off + e) * 9 + g]);
            #pragma unroll
            for (int o = 16; o > 0; o >>= 1) m = fmaxf(m, __shfl_xor(m, o));
            float s = 0.f;
            for (int e = l; e < ne; e += 32) {
                float ex = __expf(sc[(off + e) * 9 + g] - m);
                sc[(off + e) * 9 + g] = ex;
                s += ex;
            }
            #pragma unroll
            for (int o = 16; o > 0; o >>= 1) s += __shfl_xor(s, o);
            if (l == 0) ssum[rr][g] = s;
        }
    }
    __syncthreads();

    const int h = tid >> 5;
    float accA = 0.f, accB = 0.f;
    #pragma unroll 4
    for (int e = 0; e < neA; ++e)
        accA += sc[e * 9 + h] * bfu((unsigned short)valA[sidx[e] * ldA + tid]);
    #pragma unroll 4
    for (int e = 0; e < neB; ++e)
        accB += sc[(neA + e) * 9 + h] * bfu((unsigned short)valB[sidx[neA + e] * ldB + tid]);
    const float rA = fmaxf(accA / ssum[0][h], 0.f);
    const float rB = fmaxf(accB / ssum[1][h], 0.f);
    out[j * 256 + tid] = f2bf(0.5f * (rA + rB));
}

// =====================================================================
template <bool WB>
__global__ __launch_bounds__(256) void ln_k(
    float* __restrict__ data, const float* __restrict__ g,
    const float* __restrict__ b, int nrows, short* __restrict__ bfout)
{
    const int wid = threadIdx.x >> 6, lane = threadIdx.x & 63;
    const int row = blockIdx.x * 4 + wid;
    if (row >= nrows) return;
    float4 x = *reinterpret_cast<float4*>(data + row * 256 + lane * 4);
    float s  = x.x + x.y + x.z + x.w;
    float q2 = x.x * x.x + x.y * x.y + x.z * x.z + x.w * x.w;
    #pragma unroll
    for (int o = 32; o > 0; o >>= 1) { s += __shfl_xor(s, o); q2 += __shfl_xor(q2, o); }
    const float mu  = s * (1.f / 256.f);
    const float var = q2 * (1.f / 256.f) - mu * mu;
    const float rr = rsqrtf(var + 1e-5f);
    const float4 gg = *reinterpret_cast<const float4*>(g + lane * 4);
    const float4 bb = *reinterpret_cast<const float4*>(b + lane * 4);
    x.x = (x.x - mu) * rr * gg.x + bb.x;
    x.y = (x.y - mu) * rr * gg.y + bb.y;
    x.z = (x.z - mu) * rr * gg.z + bb.z;
    x.w = (x.w - mu) * rr * gg.w + bb.w;
    *reinterpret_cast<float4*>(data + row * 256 + lane * 4) = x;
    if (WB) {
        ushort4 u;
        u.x = (unsigned short)f2bf(x.x); u.y = (unsigned short)f2bf(x.y);
        u.z = (unsigned short)f2bf(x.z); u.w = (unsigned short)f2bf(x.w);
        *reinterpret_cast<ushort4*>((unsigned short*)bfout + row * 256 + lane * 4) = u;
    }
}

// =====================================================================
extern "C" void kernel_launch(void* const* d_in, const int* in_sizes, int n_in,
                              void* d_out, int out_size, void* d_ws, size_t ws_size,
                              hipStream_t stream)
{
    const float* feat_topic = (const float*)d_in[0];
    const float* feat_word  = (const float*)d_in[1];
    const float* feat_doc   = (const float*)d_in[2];
    const float* ht_prev    = (const float*)d_in[3];
    const float* Wk  = (const float*)d_in[4];
    const float* bk  = (const float*)d_in[5];
    const float* Wq  = (const float*)d_in[6];
    const float* bq  = (const float*)d_in[7];
    const float* Wv  = (const float*)d_in[8];
    const float* bv  = (const float*)d_in[9];
    const float* Wa  = (const float*)d_in[10];
    const float* ba  = (const float*)d_in[11];
    const float* ln_g = (const float*)d_in[12];
    const float* ln_b = (const float*)d_in[13];
    const float* skip = (const float*)d_in[14];
    const float* Wih  = (const float*)d_in[15];
    const float* Whh  = (const float*)d_in[16];
    const float* bih  = (const float*)d_in[17];
    const float* bhh  = (const float*)d_in[18];
    const float* rel_pri = (const float*)d_in[19];
    const float* rel_att = (const float*)d_in[20];
    const float* rel_msg = (const float*)d_in[21];
    const int* src_tt = (const int*)d_in[22];
    const int* src_wt = (const int*)d_in[24];
    const int* src_td = (const int*)d_in[26];
    const int* src_wd = (const int*)d_in[28];

    // ---- workspace layout ----
    short* B_t1 = (short*)d_ws;                 // 768*256
    short* B_w  = B_t1 + 196608;                // 1024*256
    short* B_t2 = B_w + 262144;                 // 512*256
    short* Wq2t = B_t2 + 131072;                // 5 x 256*256
    short* Whht = Wq2t + 65536;
    short* Wa0t = Whht + 65536;
    short* Wiht = Wa0t + 65536;
    short* Wa1t = Wiht + 65536;
    short* out1 = Wa1t + 65536;                 // 2000*768   (q_t | key_tt | val_tt)
    short* out2 = out1 + 1536000;               // 50000*1024 (Kwt | Vwt | Kwd | Vwd)
    short* out3 = out2 + 51200000;              // 2000*512   (Ktd | Vtd)
    short* qd   = out3 + 1024000;               // 20000*256
    short* ttop = qd + 5120000;                 // 2000*256
    short* mixb = ttop + 512000;                // 2000*256
    short* tdoc = mixb + 512000;                // 20000*256
    short* xt2  = tdoc + 5120000;               // 2000*256
    float* bias_t1 = (float*)(xt2 + 512000);    // 768
    float* bias_w  = bias_t1 + 768;             // 1024
    float* bias_t2 = bias_w + 1024;             // 512
    float* r2      = bias_t2 + 512;             // 2000*256 fp32

    float* out_topic = (float*)d_out;
    float* out_doc   = out_topic + NT * 256;

    // ---- weight prep ----
    fold_kernel<<<dim3(64), 256, 0, stream>>>(Wk, bk, Wv, bv, rel_att, rel_msg,
                                              B_t1, B_w, B_t2, bias_t1, bias_w, bias_t2);
    TransP tp;
    tp.s[0] = Wq;            tp.d[0] = B_t1;   // Wq[topic]
    tp.s[1] = Wq + 131072;   tp.d[1] = Wq2t;   // Wq[doc]
    tp.s[2] = Whh;           tp.d[2] = Whht;
    tp.s[3] = Wih;           tp.d[3] = Wiht;
    tp.s[4] = Wa;            tp.d[4] = Wa0t;
    tp.s[5] = Wa + 65536;    tp.d[5] = Wa1t;
    wtrans6<<<dim3(256, 6), 256, 0, stream>>>(tp);
    copy_bias<<<dim3(1), 256, 0, stream>>>(bq, bias_t1);

    // ---- phase-1 projections ----
    gemm_lds<true, short, 0><<<dim3(6, 16), 256, 0, stream>>>(
        feat_topic, B_t1, bias_t1, out1, NT, 768, nullptr, nullptr, 0);
    gemm_lds<true, short, 0><<<dim3(8, 391), 256, 0, stream>>>(
        feat_word, B_w, bias_w, out2, NW, 1024, nullptr, nullptr, 0);
    gemm_lds<true, short, 0><<<dim3(2, 157), 256, 0, stream>>>(
        feat_doc, Wq2t, bq + 512, qd, ND, 256, nullptr, nullptr, 0);
    gemm_lds<true, float, 0><<<dim3(2, 16), 256, 0, stream>>>(
        ht_prev, Whht, bhh, r2, NT, 256, nullptr, nullptr, 0);

    // ---- messages into topic (tt:64/dst, wt:128/dst) ----
    msg_k<<<dim3(NT), 256, 0, stream>>>(
        out1, 768,
        out1 + 256, out1 + 512, 768, src_tt, 64,
        out2, out2 + 256, 1024, src_wt, 128,
        rel_pri, 0, 1, ttop, NT);

    // ---- topic update: mix -> RNN tanh -> LN ----
    gemm_lds<false, short, 1><<<dim3(2, 16), 256, 0, stream>>>(
        ttop, Wa0t, ba, mixb, NT, 256, feat_topic, skip, 0);
    gemm_lds<false, float, 2><<<dim3(2, 16), 256, 0, stream>>>(
        mixb, Wiht, bih, out_topic, NT, 256, r2, nullptr, 0);
    ln_k<true><<<dim3(500), 256, 0, stream>>>(out_topic, ln_g, ln_b, NT, xt2);

    // ---- phase-2 topic projections ----
    gemm_lds<false, short, 0><<<dim3(4, 16), 256, 0, stream>>>(
        xt2, B_t2, bias_t2, out3, NT, 512, nullptr, nullptr, 0);

    // ---- messages into doc (td:16/dst, wd:16/dst) ----
    msg_k<<<dim3(ND), 256, 0, stream>>>(
        qd, 256,
        out3, out3 + 256, 512, src_td, 16,
        out2 + 512, out2 + 768, 1024, src_wd, 16,
        rel_pri, 2, 3, tdoc, ND);

    // ---- doc update: mix -> LN ----
    gemm_lds<false, float, 1><<<dim3(2, 157), 256, 0, stream>>>(
        tdoc, Wa1t, ba + 256, out_doc, ND, 256, feat_doc, skip, 1);
    ln_k<false><<<dim3(5000), 256, 0, stream>>>(out_doc, ln_g + 256, ln_b + 256, ND, nullptr);
}

// Round 4
// 372.787 us; speedup vs baseline: 2.7039x; 1.2802x over previous
//
#include <hip/hip_runtime.h>
#include <hip/hip_bf16.h>

typedef __attribute__((ext_vector_type(8))) short bf16x8;
typedef __attribute__((ext_vector_type(4))) float f32x4;

constexpr int NT = 2000, NW = 50000, ND = 20000;
constexpr float INV_SQRT_DK = 0.17677669529663687f;  // 1/sqrt(32)

__device__ inline float bfu(unsigned short u) {
    return __uint_as_float(((unsigned int)u) << 16);
}
__device__ inline float blo(unsigned int u) { return __uint_as_float(u << 16); }
__device__ inline float bhi(unsigned int u) { return __uint_as_float(u & 0xffff0000u); }
__device__ inline short f2bf(float x) {
    __hip_bfloat16 h = __float2bfloat16(x);
    short s; __builtin_memcpy(&s, &h, 2); return s;
}
__device__ inline void cstore(float* p, float v) { *p = v; }
__device__ inline void cstore(short* p, float v) { *p = f2bf(v); }

__device__ inline void gload16(const short* g, short* l) {
    __builtin_amdgcn_global_load_lds(
        (const __attribute__((address_space(1))) void*)g,
        (__attribute__((address_space(3))) void*)l, 16, 0, 0);
}

// 32-element bf16 dot with fp32 q (qh group-uniform broadcast from LDS)
__device__ inline float dot32(const short* __restrict__ kp, const float* __restrict__ qh) {
    const uint4* p = reinterpret_cast<const uint4*>(kp);
    float d = 0.f;
    #pragma unroll
    for (int c = 0; c < 4; ++c) {
        const uint4 u = p[c];
        d += qh[c * 8 + 0] * blo(u.x) + qh[c * 8 + 1] * bhi(u.x)
           + qh[c * 8 + 2] * blo(u.y) + qh[c * 8 + 3] * bhi(u.y)
           + qh[c * 8 + 4] * blo(u.z) + qh[c * 8 + 5] * bhi(u.z)
           + qh[c * 8 + 6] * blo(u.w) + qh[c * 8 + 7] * bhi(u.w);
    }
    return d;
}

// =====================================================================
// fold: per-relation head transforms folded into projection weights,
// written TRANSPOSED bf16 ([n][k]) into the packed B matrices.
// =====================================================================
__global__ __launch_bounds__(256) void fold_kernel(
    const float* __restrict__ Wk, const float* __restrict__ bk,
    const float* __restrict__ Wv, const float* __restrict__ bv,
    const float* __restrict__ rel_att, const float* __restrict__ rel_msg,
    short* __restrict__ B_t1, short* __restrict__ B_w, short* __restrict__ B_t2,
    float* __restrict__ bias_t1, float* __restrict__ bias_w, float* __restrict__ bias_t2)
{
    const int f = blockIdx.x >> 3, chunk = blockIdx.x & 7;
    const int rel = f >> 1, isV = f & 1;
    const int ntype = (rel == 1 || rel == 3) ? 1 : 0;
    const float* Wsrc = (isV ? Wv : Wk) + ntype * 65536;
    const float* bsrc = (isV ? bv : bk) + ntype * 256;
    const float* A    = (isV ? rel_msg : rel_att) + rel * 8192;  // [8][32][32]
    short* wdst; float* bdst;
    switch (f) {
        case 0: wdst = B_t1 + 65536;     bdst = bias_t1 + 256; break;  // K tt
        case 1: wdst = B_t1 + 2 * 65536; bdst = bias_t1 + 512; break;  // V tt
        case 2: wdst = B_w;              bdst = bias_w;        break;  // K wt
        case 3: wdst = B_w + 65536;      bdst = bias_w + 256;  break;  // V wt
        case 4: wdst = B_t2;             bdst = bias_t2;       break;  // K td
        case 5: wdst = B_t2 + 65536;     bdst = bias_t2 + 256; break;  // V td
        case 6: wdst = B_w + 2 * 65536;  bdst = bias_w + 512;  break;  // K wd
        default: wdst = B_w + 3 * 65536; bdst = bias_w + 768;  break;  // V wd
    }
    __shared__ float Wsh[32][256];
    const int tid = threadIdx.x;
    for (int i = 0; i < 32; ++i)
        Wsh[i][tid] = Wsrc[(chunk * 32 + i) * 256 + tid];
    __syncthreads();
    const int h = tid >> 5, o = tid & 31;
    float a[32];
    #pragma unroll
    for (int d = 0; d < 32; ++d) a[d] = A[h * 1024 + d * 32 + o];
    short tmp[32];
    #pragma unroll
    for (int r = 0; r < 32; ++r) {
        float s = 0.f;
        #pragma unroll
        for (int d = 0; d < 32; ++d) s = fmaf(Wsh[r][(h << 5) + d], a[d], s);
        tmp[r] = f2bf(s);
    }
    short* wp = wdst + tid * 256 + chunk * 32;
    #pragma unroll
    for (int r8 = 0; r8 < 4; ++r8) {
        bf16x8 v;
        #pragma unroll
        for (int t = 0; t < 8; ++t) v[t] = tmp[r8 * 8 + t];
        *reinterpret_cast<bf16x8*>(wp + r8 * 8) = v;
    }
    if (chunk == 0) {
        float s = 0.f;
        #pragma unroll
        for (int d = 0; d < 32; ++d) s = fmaf(bsrc[(h << 5) + d], a[d], s);
        bdst[tid] = s;
    }
}

struct TransP { const float* s[6]; short* d[6]; };
__global__ __launch_bounds__(256) void wtrans6(TransP p) {
    const int m = blockIdx.y, n = blockIdx.x, k = threadIdx.x;
    p.d[m][n * 256 + k] = f2bf(p.s[m][k * 256 + n]);
}

__global__ void copy_bias(const float* __restrict__ s, float* __restrict__ d) {
    d[threadIdx.x] = s[threadIdx.x];
}

// =====================================================================
// LDS-staged MFMA GEMM (m97 structure), unchanged from round 3.
// =====================================================================
template <bool XF32, typename OutT, int EPI>
__global__ __launch_bounds__(256) void gemm_lds(
    const void* __restrict__ Xv, const short* __restrict__ Wt,
    const float* __restrict__ bias, OutT* __restrict__ C,
    int M, int ldc, const float* __restrict__ extra,
    const float* __restrict__ skipv, int skipIdx)
{
    __shared__ short As[128 * 64];
    __shared__ short Bs[128 * 64];
    const int tid = threadIdx.x;
    const int wave = tid >> 6, lane = tid & 63;
    const int wm = wave >> 1, wn = wave & 1;
    const int r = lane & 15, kb = lane >> 4;
    const int col0 = blockIdx.x * 128;
    const int row0 = blockIdx.y * 128;

    const int l8 = lane >> 3;
    const int c8 = lane & 7;
    const int swz8 = c8 ^ l8;
    f32x4 acc[4][4] = {};

    for (int k0 = 0; k0 < 256; k0 += 64) {
        if (k0) __syncthreads();
        if constexpr (XF32) {
            #pragma unroll
            for (int q = 0; q < 4; ++q) {
                const int rl = wave * 32 + q * 8 + l8;
                const int grow = min(row0 + rl, M - 1);
                const float* xp = (const float*)Xv + grow * 256 + k0 + c8 * 8;
                const float4 x0 = *reinterpret_cast<const float4*>(xp);
                const float4 x1 = *reinterpret_cast<const float4*>(xp + 4);
                bf16x8 v;
                v[0] = f2bf(x0.x); v[1] = f2bf(x0.y); v[2] = f2bf(x0.z); v[3] = f2bf(x0.w);
                v[4] = f2bf(x1.x); v[5] = f2bf(x1.y); v[6] = f2bf(x1.z); v[7] = f2bf(x1.w);
                *reinterpret_cast<bf16x8*>(As + rl * 64 + swz8 * 8) = v;
            }
        } else {
            #pragma unroll
            for (int q = 0; q < 4; ++q) {
                const int rl = wave * 32 + q * 8 + l8;
                const int grow = min(row0 + rl, M - 1);
                gload16((const short*)Xv + grow * 256 + k0 + swz8 * 8,
                        As + (wave * 32 + q * 8) * 64);
            }
        }
        #pragma unroll
        for (int q = 0; q < 4; ++q) {
            const int cl = wave * 32 + q * 8 + l8;
            gload16(Wt + (col0 + cl) * 256 + k0 + swz8 * 8,
                    Bs + (wave * 32 + q * 8) * 64);
        }
        __syncthreads();
        #pragma unroll
        for (int s = 0; s < 2; ++s) {
            const int csw = ((kb + 4 * s) ^ (r & 7)) * 8;
            bf16x8 af[4], bw[4];
            #pragma unroll
            for (int i = 0; i < 4; ++i) {
                af[i] = *reinterpret_cast<const bf16x8*>(As + (wm * 64 + i * 16 + r) * 64 + csw);
                bw[i] = *reinterpret_cast<const bf16x8*>(Bs + (wn * 64 + i * 16 + r) * 64 + csw);
            }
            #pragma unroll
            for (int i = 0; i < 4; ++i)
                #pragma unroll
                for (int j = 0; j < 4; ++j)
                    acc[i][j] = __builtin_amdgcn_mfma_f32_16x16x32_bf16(af[i], bw[j], acc[i][j], 0, 0, 0);
        }
    }

    float alpha = 0.f;
    if (EPI == 1) alpha = 1.f / (1.f + __expf(-skipv[skipIdx]));
    #pragma unroll
    for (int i = 0; i < 4; ++i) {
        #pragma unroll
        for (int j = 0; j < 4; ++j) {
            const int col = col0 + wn * 64 + j * 16 + r;
            const float bc = bias[col];
            #pragma unroll
            for (int t = 0; t < 4; ++t) {
                const int rrow = row0 + wm * 64 + i * 16 + kb * 4 + t;
                if (rrow < M) {
                    float v = acc[i][j][t] + bc;
                    if (EPI == 1) v = alpha * v + (1.f - alpha) * extra[rrow * 256 + col];
                    if (EPI == 2) v = tanhf(v + extra[rrow * 256 + col]);
                    cstore(C + rrow * ldc + col, v);
                }
            }
        }
    }
}

// =====================================================================
// msg_k round 4: per-head score groups, register softmax (pre-divided),
// 16B-wide accumulate with 8 edge-slots x 32 col-threads + LDS reduce.
// =====================================================================
template <int NE>
__device__ inline void rel_scores(const short* __restrict__ key, int ld,
                                  const int* __restrict__ sidx, int off, float scale,
                                  const float* __restrict__ qh, float* __restrict__ sc,
                                  int g, int l)
{
    constexpr int NL = NE / 32;
    float att[NL];
    #pragma unroll
    for (int t = 0; t < NL; ++t) {
        const int src = sidx[off + l + 32 * t];
        att[t] = dot32(key + src * ld + g * 32, qh) * scale;
    }
    float m = att[0];
    #pragma unroll
    for (int t = 1; t < NL; ++t) m = fmaxf(m, att[t]);
    #pragma unroll
    for (int o = 16; o > 0; o >>= 1) m = fmaxf(m, __shfl_xor(m, o));
    float ex[NL], s = 0.f;
    #pragma unroll
    for (int t = 0; t < NL; ++t) { ex[t] = __expf(att[t] - m); s += ex[t]; }
    #pragma unroll
    for (int o = 16; o > 0; o >>= 1) s += __shfl_xor(s, o);
    const float inv = 1.f / s;
    #pragma unroll
    for (int t = 0; t < NL; ++t) sc[(off + l + 32 * t) * 9 + g] = ex[t] * inv;
}

template <int NE>
__device__ inline void accum_rel(const short* __restrict__ val, int ld,
                                 const int* __restrict__ sidx, int off,
                                 const float* __restrict__ sc,
                                 int es, int ct, int h, float* __restrict__ acc)
{
    #pragma unroll
    for (int e = es; e < NE; e += 8) {
        const float w = sc[(off + e) * 9 + h];
        const uint4 u = *reinterpret_cast<const uint4*>(val + sidx[off + e] * ld + ct * 8);
        acc[0] = fmaf(w, blo(u.x), acc[0]);
        acc[1] = fmaf(w, bhi(u.x), acc[1]);
        acc[2] = fmaf(w, blo(u.y), acc[2]);
        acc[3] = fmaf(w, bhi(u.y), acc[3]);
        acc[4] = fmaf(w, blo(u.z), acc[4]);
        acc[5] = fmaf(w, bhi(u.z), acc[5]);
        acc[6] = fmaf(w, blo(u.w), acc[6]);
        acc[7] = fmaf(w, bhi(u.w), acc[7]);
    }
}

template <int NEA, int NEB>
__global__ __launch_bounds__(256) void msg_k(
    const short* __restrict__ q, int ldq,
    const short* __restrict__ keyA, const short* __restrict__ valA, int ldA,
    const int* __restrict__ srcA,
    const short* __restrict__ keyB, const short* __restrict__ valB, int ldB,
    const int* __restrict__ srcB,
    const float* __restrict__ relPri, int relA, int relB,
    short* __restrict__ out, int n_dst)
{
    constexpr int NET = NEA + NEB;
    const int j = blockIdx.x, tid = threadIdx.x;
    __shared__ float qsh[256];
    __shared__ int sidx[NET];
    __shared__ float sc[NET * 9];
    __shared__ float psA[8][256];
    __shared__ float psB[8][256];

    qsh[tid] = bfu((unsigned short)q[j * ldq + tid]);
    if (tid < NEA) sidx[tid] = srcA[j + tid * n_dst];
    else if (tid < NET) sidx[tid] = srcB[j + (tid - NEA) * n_dst];
    __syncthreads();

    const int g = tid >> 5, l = tid & 31;
    const float* qh = qsh + g * 32;

    if constexpr (NEA == 16 && NEB == 16) {
        const int rel = l >> 4, e = l & 15, off = rel * 16;
        const float scale = relPri[(rel ? relB : relA) * 8 + g] * INV_SQRT_DK;
        const short* key = rel ? keyB : keyA;
        const int ld = rel ? ldB : ldA;
        const float att = dot32(key + sidx[off + e] * ld + g * 32, qh) * scale;
        float m = att;
        #pragma unroll
        for (int o = 8; o > 0; o >>= 1) m = fmaxf(m, __shfl_xor(m, o));
        const float ex = __expf(att - m);
        float s = ex;
        #pragma unroll
        for (int o = 8; o > 0; o >>= 1) s += __shfl_xor(s, o);
        sc[(off + e) * 9 + g] = ex / s;
    } else {
        rel_scores<NEA>(keyA, ldA, sidx, 0,   relPri[relA * 8 + g] * INV_SQRT_DK, qh, sc, g, l);
        rel_scores<NEB>(keyB, ldB, sidx, NEA, relPri[relB * 8 + g] * INV_SQRT_DK, qh, sc, g, l);
    }
    __syncthreads();

    const int es = tid >> 5, ct = tid & 31, hh = ct >> 2;
    float accA[8] = {}, accB[8] = {};
    accum_rel<NEA>(valA, ldA, sidx, 0,   sc, es, ct, hh, accA);
    accum_rel<NEB>(valB, ldB, sidx, NEA, sc, es, ct, hh, accB);
    *reinterpret_cast<float4*>(&psA[es][ct * 8])     = make_float4(accA[0], accA[1], accA[2], accA[3]);
    *reinterpret_cast<float4*>(&psA[es][ct * 8 + 4]) = make_float4(accA[4], accA[5], accA[6], accA[7]);
    *reinterpret_cast<float4*>(&psB[es][ct * 8])     = make_float4(accB[0], accB[1], accB[2], accB[3]);
    *reinterpret_cast<float4*>(&psB[es][ct * 8 + 4]) = make_float4(accB[4], accB[5], accB[6], accB[7]);
    __syncthreads();

    float rA = 0.f, rB = 0.f;
    #pragma unroll
    for (int e2 = 0; e2 < 8; ++e2) { rA += psA[e2][tid]; rB += psB[e2][tid]; }
    out[j * 256 + tid] = f2bf(0.5f * (fmaxf(rA, 0.f) + fmaxf(rB, 0.f)));
}

// =====================================================================
template <bool WB>
__global__ __launch_bounds__(256) void ln_k(
    float* __restrict__ data, const float* __restrict__ g,
    const float* __restrict__ b, int nrows, short* __restrict__ bfout)
{
    const int wid = threadIdx.x >> 6, lane = threadIdx.x & 63;
    const int row = blockIdx.x * 4 + wid;
    if (row >= nrows) return;
    float4 x = *reinterpret_cast<float4*>(data + row * 256 + lane * 4);
    float s  = x.x + x.y + x.z + x.w;
    float q2 = x.x * x.x + x.y * x.y + x.z * x.z + x.w * x.w;
    #pragma unroll
    for (int o = 32; o > 0; o >>= 1) { s += __shfl_xor(s, o); q2 += __shfl_xor(q2, o); }
    const float mu  = s * (1.f / 256.f);
    const float var = q2 * (1.f / 256.f) - mu * mu;
    const float rr = rsqrtf(var + 1e-5f);
    const float4 gg = *reinterpret_cast<const float4*>(g + lane * 4);
    const float4 bb = *reinterpret_cast<const float4*>(b + lane * 4);
    x.x = (x.x - mu) * rr * gg.x + bb.x;
    x.y = (x.y - mu) * rr * gg.y + bb.y;
    x.z = (x.z - mu) * rr * gg.z + bb.z;
    x.w = (x.w - mu) * rr * gg.w + bb.w;
    *reinterpret_cast<float4*>(data + row * 256 + lane * 4) = x;
    if (WB) {
        ushort4 u;
        u.x = (unsigned short)f2bf(x.x); u.y = (unsigned short)f2bf(x.y);
        u.z = (unsigned short)f2bf(x.z); u.w = (unsigned short)f2bf(x.w);
        *reinterpret_cast<ushort4*>((unsigned short*)bfout + row * 256 + lane * 4) = u;
    }
}

// =====================================================================
extern "C" void kernel_launch(void* const* d_in, const int* in_sizes, int n_in,
                              void* d_out, int out_size, void* d_ws, size_t ws_size,
                              hipStream_t stream)
{
    const float* feat_topic = (const float*)d_in[0];
    const float* feat_word  = (const float*)d_in[1];
    const float* feat_doc   = (const float*)d_in[2];
    const float* ht_prev    = (const float*)d_in[3];
    const float* Wk  = (const float*)d_in[4];
    const float* bk  = (const float*)d_in[5];
    const float* Wq  = (const float*)d_in[6];
    const float* bq  = (const float*)d_in[7];
    const float* Wv  = (const float*)d_in[8];
    const float* bv  = (const float*)d_in[9];
    const float* Wa  = (const float*)d_in[10];
    const float* ba  = (const float*)d_in[11];
    const float* ln_g = (const float*)d_in[12];
    const float* ln_b = (const float*)d_in[13];
    const float* skip = (const float*)d_in[14];
    const float* Wih  = (const float*)d_in[15];
    const float* Whh  = (const float*)d_in[16];
    const float* bih  = (const float*)d_in[17];
    const float* bhh  = (const float*)d_in[18];
    const float* rel_pri = (const float*)d_in[19];
    const float* rel_att = (const float*)d_in[20];
    const float* rel_msg = (const float*)d_in[21];
    const int* src_tt = (const int*)d_in[22];
    const int* src_wt = (const int*)d_in[24];
    const int* src_td = (const int*)d_in[26];
    const int* src_wd = (const int*)d_in[28];

    // ---- workspace layout ----
    short* B_t1 = (short*)d_ws;                 // 768*256
    short* B_w  = B_t1 + 196608;                // 1024*256
    short* B_t2 = B_w + 262144;                 // 512*256
    short* Wq2t = B_t2 + 131072;                // 5 x 256*256
    short* Whht = Wq2t + 65536;
    short* Wa0t = Whht + 65536;
    short* Wiht = Wa0t + 65536;
    short* Wa1t = Wiht + 65536;
    short* out1 = Wa1t + 65536;                 // 2000*768   (q_t | key_tt | val_tt)
    short* out2 = out1 + 1536000;               // 50000*1024 (Kwt | Vwt | Kwd | Vwd)
    short* out3 = out2 + 51200000;              // 2000*512   (Ktd | Vtd)
    short* qd   = out3 + 1024000;               // 20000*256
    short* ttop = qd + 5120000;                 // 2000*256
    short* mixb = ttop + 512000;                // 2000*256
    short* tdoc = mixb + 512000;                // 20000*256
    short* xt2  = tdoc + 5120000;               // 2000*256
    float* bias_t1 = (float*)(xt2 + 512000);    // 768
    float* bias_w  = bias_t1 + 768;             // 1024
    float* bias_t2 = bias_w + 1024;             // 512
    float* r2      = bias_t2 + 512;             // 2000*256 fp32

    float* out_topic = (float*)d_out;
    float* out_doc   = out_topic + NT * 256;

    // ---- weight prep ----
    fold_kernel<<<dim3(64), 256, 0, stream>>>(Wk, bk, Wv, bv, rel_att, rel_msg,
                                              B_t1, B_w, B_t2, bias_t1, bias_w, bias_t2);
    TransP tp;
    tp.s[0] = Wq;            tp.d[0] = B_t1;   // Wq[topic]
    tp.s[1] = Wq + 131072;   tp.d[1] = Wq2t;   // Wq[doc]
    tp.s[2] = Whh;           tp.d[2] = Whht;
    tp.s[3] = Wih;           tp.d[3] = Wiht;
    tp.s[4] = Wa;            tp.d[4] = Wa0t;
    tp.s[5] = Wa + 65536;    tp.d[5] = Wa1t;
    wtrans6<<<dim3(256, 6), 256, 0, stream>>>(tp);
    copy_bias<<<dim3(1), 256, 0, stream>>>(bq, bias_t1);

    // ---- phase-1 projections ----
    gemm_lds<true, short, 0><<<dim3(6, 16), 256, 0, stream>>>(
        feat_topic, B_t1, bias_t1, out1, NT, 768, nullptr, nullptr, 0);
    gemm_lds<true, short, 0><<<dim3(8, 391), 256, 0, stream>>>(
        feat_word, B_w, bias_w, out2, NW, 1024, nullptr, nullptr, 0);
    gemm_lds<true, short, 0><<<dim3(2, 157), 256, 0, stream>>>(
        feat_doc, Wq2t, bq + 512, qd, ND, 256, nullptr, nullptr, 0);
    gemm_lds<true, float, 0><<<dim3(2, 16), 256, 0, stream>>>(
        ht_prev, Whht, bhh, r2, NT, 256, nullptr, nullptr, 0);

    // ---- messages into topic (tt:64/dst, wt:128/dst) ----
    msg_k<64, 128><<<dim3(NT), 256, 0, stream>>>(
        out1, 768,
        out1 + 256, out1 + 512, 768, src_tt,
        out2, out2 + 256, 1024, src_wt,
        rel_pri, 0, 1, ttop, NT);

    // ---- topic update: mix -> RNN tanh -> LN ----
    gemm_lds<false, short, 1><<<dim3(2, 16), 256, 0, stream>>>(
        ttop, Wa0t, ba, mixb, NT, 256, feat_topic, skip, 0);
    gemm_lds<false, float, 2><<<dim3(2, 16), 256, 0, stream>>>(
        mixb, Wiht, bih, out_topic, NT, 256, r2, nullptr, 0);
    ln_k<true><<<dim3(500), 256, 0, stream>>>(out_topic, ln_g, ln_b, NT, xt2);

    // ---- phase-2 topic projections ----
    gemm_lds<false, short, 0><<<dim3(4, 16), 256, 0, stream>>>(
        xt2, B_t2, bias_t2, out3, NT, 512, nullptr, nullptr, 0);

    // ---- messages into doc (td:16/dst, wd:16/dst) ----
    msg_k<16, 16><<<dim3(ND), 256, 0, stream>>>(
        qd, 256,
        out3, out3 + 256, 512, src_td,
        out2 + 512, out2 + 768, 1024, src_wd,
        rel_pri, 2, 3, tdoc, ND);

    // ---- doc update: mix -> LN ----
    gemm_lds<false, float, 1><<<dim3(2, 157), 256, 0, stream>>>(
        tdoc, Wa1t, ba + 256, out_doc, ND, 256, feat_doc, skip, 1);
    ln_k<false><<<dim3(5000), 256, 0, stream>>>(out_doc, ln_g + 256, ln_b + 256, ND, nullptr);
}

// Round 5
// 352.664 us; speedup vs baseline: 2.8582x; 1.0571x over previous
//
#include <hip/hip_runtime.h>
#include <hip/hip_bf16.h>

typedef __attribute__((ext_vector_type(8))) short bf16x8;
typedef __attribute__((ext_vector_type(4))) float f32x4;

constexpr int NT = 2000, NW = 50000, ND = 20000;
constexpr float INV_SQRT_DK = 0.17677669529663687f;  // 1/sqrt(32)

__device__ inline float bfu(unsigned short u) {
    return __uint_as_float(((unsigned int)u) << 16);
}
__device__ inline float blo(unsigned int u) { return __uint_as_float(u << 16); }
__device__ inline float bhi(unsigned int u) { return __uint_as_float(u & 0xffff0000u); }
__device__ inline short f2bf(float x) {
    __hip_bfloat16 h = __float2bfloat16(x);
    short s; __builtin_memcpy(&s, &h, 2); return s;
}
__device__ inline void cstore(float* p, float v) { *p = v; }
__device__ inline void cstore(short* p, float v) { *p = f2bf(v); }

__device__ inline void gload16(const short* g, short* l) {
    __builtin_amdgcn_global_load_lds(
        (const __attribute__((address_space(1))) void*)g,
        (__attribute__((address_space(3))) void*)l, 16, 0, 0);
}

// 32-element bf16 dot with fp32 q (qh group-uniform broadcast from LDS)
__device__ inline float dot32(const short* __restrict__ kp, const float* __restrict__ qh) {
    const uint4* p = reinterpret_cast<const uint4*>(kp);
    float d = 0.f;
    #pragma unroll
    for (int c = 0; c < 4; ++c) {
        const uint4 u = p[c];
        d += qh[c * 8 + 0] * blo(u.x) + qh[c * 8 + 1] * bhi(u.x)
           + qh[c * 8 + 2] * blo(u.y) + qh[c * 8 + 3] * bhi(u.y)
           + qh[c * 8 + 4] * blo(u.z) + qh[c * 8 + 5] * bhi(u.z)
           + qh[c * 8 + 6] * blo(u.w) + qh[c * 8 + 7] * bhi(u.w);
    }
    return d;
}

// =====================================================================
// fp32 -> bf16 convert (vectorized, grid-stride); n8 = count/8
// =====================================================================
__global__ __launch_bounds__(256) void cvt_bf16(
    const float* __restrict__ src, short* __restrict__ dst, int n8)
{
    const int stride = gridDim.x * 256;
    for (int i = blockIdx.x * 256 + threadIdx.x; i < n8; i += stride) {
        const float* p = src + (long)i * 8;
        const float4 x0 = *reinterpret_cast<const float4*>(p);
        const float4 x1 = *reinterpret_cast<const float4*>(p + 4);
        bf16x8 v;
        v[0] = f2bf(x0.x); v[1] = f2bf(x0.y); v[2] = f2bf(x0.z); v[3] = f2bf(x0.w);
        v[4] = f2bf(x1.x); v[5] = f2bf(x1.y); v[6] = f2bf(x1.z); v[7] = f2bf(x1.w);
        *reinterpret_cast<bf16x8*>(dst + (long)i * 8) = v;
    }
}

// =====================================================================
// fold: per-relation head transforms folded into projection weights,
// written TRANSPOSED bf16 ([n][k]) into the packed B matrices.
// =====================================================================
__global__ __launch_bounds__(256) void fold_kernel(
    const float* __restrict__ Wk, const float* __restrict__ bk,
    const float* __restrict__ Wv, const float* __restrict__ bv,
    const float* __restrict__ rel_att, const float* __restrict__ rel_msg,
    short* __restrict__ B_t1, short* __restrict__ B_w, short* __restrict__ B_t2,
    float* __restrict__ bias_t1, float* __restrict__ bias_w, float* __restrict__ bias_t2)
{
    const int f = blockIdx.x >> 3, chunk = blockIdx.x & 7;
    const int rel = f >> 1, isV = f & 1;
    const int ntype = (rel == 1 || rel == 3) ? 1 : 0;
    const float* Wsrc = (isV ? Wv : Wk) + ntype * 65536;
    const float* bsrc = (isV ? bv : bk) + ntype * 256;
    const float* A    = (isV ? rel_msg : rel_att) + rel * 8192;  // [8][32][32]
    short* wdst; float* bdst;
    switch (f) {
        case 0: wdst = B_t1 + 65536;     bdst = bias_t1 + 256; break;  // K tt
        case 1: wdst = B_t1 + 2 * 65536; bdst = bias_t1 + 512; break;  // V tt
        case 2: wdst = B_w;              bdst = bias_w;        break;  // K wt
        case 3: wdst = B_w + 65536;      bdst = bias_w + 256;  break;  // V wt
        case 4: wdst = B_t2;             bdst = bias_t2;       break;  // K td
        case 5: wdst = B_t2 + 65536;     bdst = bias_t2 + 256; break;  // V td
        case 6: wdst = B_w + 2 * 65536;  bdst = bias_w + 512;  break;  // K wd
        default: wdst = B_w + 3 * 65536; bdst = bias_w + 768;  break;  // V wd
    }
    __shared__ float Wsh[32][256];
    const int tid = threadIdx.x;
    for (int i = 0; i < 32; ++i)
        Wsh[i][tid] = Wsrc[(chunk * 32 + i) * 256 + tid];
    __syncthreads();
    const int h = tid >> 5, o = tid & 31;
    float a[32];
    #pragma unroll
    for (int d = 0; d < 32; ++d) a[d] = A[h * 1024 + d * 32 + o];
    short tmp[32];
    #pragma unroll
    for (int r = 0; r < 32; ++r) {
        float s = 0.f;
        #pragma unroll
        for (int d = 0; d < 32; ++d) s = fmaf(Wsh[r][(h << 5) + d], a[d], s);
        tmp[r] = f2bf(s);
    }
    short* wp = wdst + tid * 256 + chunk * 32;
    #pragma unroll
    for (int r8 = 0; r8 < 4; ++r8) {
        bf16x8 v;
        #pragma unroll
        for (int t = 0; t < 8; ++t) v[t] = tmp[r8 * 8 + t];
        *reinterpret_cast<bf16x8*>(wp + r8 * 8) = v;
    }
    if (chunk == 0) {
        float s = 0.f;
        #pragma unroll
        for (int d = 0; d < 32; ++d) s = fmaf(bsrc[(h << 5) + d], a[d], s);
        bdst[tid] = s;
    }
}

struct TransP { const float* s[6]; short* d[6]; };
__global__ __launch_bounds__(256) void wtrans6(TransP p) {
    const int m = blockIdx.y, n = blockIdx.x, k = threadIdx.x;
    p.d[m][n * 256 + k] = f2bf(p.s[m][k * 256 + n]);
}

__global__ void copy_bias(const float* __restrict__ s, float* __restrict__ d) {
    d[threadIdx.x] = s[threadIdx.x];
}

// =====================================================================
// LDS-staged MFMA GEMM (m97 structure). SWZ: XCD-colocating remap for
// grid (8, RT+pad) so the 8 col-tiles sharing an A row-tile land on the
// same XCD L2 (kills the 4x A re-fetch).
// =====================================================================
template <bool XF32, typename OutT, int EPI, bool SWZ>
__global__ __launch_bounds__(256) void gemm_lds(
    const void* __restrict__ Xv, const short* __restrict__ Wt,
    const float* __restrict__ bias, OutT* __restrict__ C,
    int M, int ldc, const float* __restrict__ extra,
    const float* __restrict__ skipv, int skipIdx)
{
    __shared__ short As[128 * 64];
    __shared__ short Bs[128 * 64];
    int bxi = blockIdx.x, byi = blockIdx.y;
    if constexpr (SWZ) {
        const int h = bxi + (int)gridDim.x * byi;
        const int i = h >> 3;
        byi = (h & 7) + 8 * (i >> 3);
        bxi = i & 7;
        if (byi * 128 >= M) return;
    }
    const int tid = threadIdx.x;
    const int wave = tid >> 6, lane = tid & 63;
    const int wm = wave >> 1, wn = wave & 1;
    const int r = lane & 15, kb = lane >> 4;
    const int col0 = bxi * 128;
    const int row0 = byi * 128;

    const int l8 = lane >> 3;
    const int c8 = lane & 7;
    const int swz8 = c8 ^ l8;
    f32x4 acc[4][4] = {};

    for (int k0 = 0; k0 < 256; k0 += 64) {
        if (k0) __syncthreads();
        if constexpr (XF32) {
            #pragma unroll
            for (int q = 0; q < 4; ++q) {
                const int rl = wave * 32 + q * 8 + l8;
                const int grow = min(row0 + rl, M - 1);
                const float* xp = (const float*)Xv + grow * 256 + k0 + c8 * 8;
                const float4 x0 = *reinterpret_cast<const float4*>(xp);
                const float4 x1 = *reinterpret_cast<const float4*>(xp + 4);
                bf16x8 v;
                v[0] = f2bf(x0.x); v[1] = f2bf(x0.y); v[2] = f2bf(x0.z); v[3] = f2bf(x0.w);
                v[4] = f2bf(x1.x); v[5] = f2bf(x1.y); v[6] = f2bf(x1.z); v[7] = f2bf(x1.w);
                *reinterpret_cast<bf16x8*>(As + rl * 64 + swz8 * 8) = v;
            }
        } else {
            #pragma unroll
            for (int q = 0; q < 4; ++q) {
                const int rl = wave * 32 + q * 8 + l8;
                const int grow = min(row0 + rl, M - 1);
                gload16((const short*)Xv + grow * 256 + k0 + swz8 * 8,
                        As + (wave * 32 + q * 8) * 64);
            }
        }
        #pragma unroll
        for (int q = 0; q < 4; ++q) {
            const int cl = wave * 32 + q * 8 + l8;
            gload16(Wt + (col0 + cl) * 256 + k0 + swz8 * 8,
                    Bs + (wave * 32 + q * 8) * 64);
        }
        __syncthreads();
        #pragma unroll
        for (int s = 0; s < 2; ++s) {
            const int csw = ((kb + 4 * s) ^ (r & 7)) * 8;
            bf16x8 af[4], bw[4];
            #pragma unroll
            for (int i = 0; i < 4; ++i) {
                af[i] = *reinterpret_cast<const bf16x8*>(As + (wm * 64 + i * 16 + r) * 64 + csw);
                bw[i] = *reinterpret_cast<const bf16x8*>(Bs + (wn * 64 + i * 16 + r) * 64 + csw);
            }
            #pragma unroll
            for (int i = 0; i < 4; ++i)
                #pragma unroll
                for (int j = 0; j < 4; ++j)
                    acc[i][j] = __builtin_amdgcn_mfma_f32_16x16x32_bf16(af[i], bw[j], acc[i][j], 0, 0, 0);
        }
    }

    float alpha = 0.f;
    if (EPI == 1) alpha = 1.f / (1.f + __expf(-skipv[skipIdx]));
    #pragma unroll
    for (int i = 0; i < 4; ++i) {
        #pragma unroll
        for (int j = 0; j < 4; ++j) {
            const int col = col0 + wn * 64 + j * 16 + r;
            const float bc = bias[col];
            #pragma unroll
            for (int t = 0; t < 4; ++t) {
                const int rrow = row0 + wm * 64 + i * 16 + kb * 4 + t;
                if (rrow < M) {
                    float v = acc[i][j][t] + bc;
                    if (EPI == 1) v = alpha * v + (1.f - alpha) * extra[rrow * 256 + col];
                    if (EPI == 2) v = tanhf(v + extra[rrow * 256 + col]);
                    cstore(C + rrow * ldc + col, v);
                }
            }
        }
    }
}

// =====================================================================
// msg_k: per-head score groups, register softmax (pre-divided),
// 16B-wide accumulate with 8 edge-slots x 32 col-threads + LDS reduce.
// =====================================================================
template <int NE>
__device__ inline void rel_scores(const short* __restrict__ key, int ld,
                                  const int* __restrict__ sidx, int off, float scale,
                                  const float* __restrict__ qh, float* __restrict__ sc,
                                  int g, int l)
{
    constexpr int NL = NE / 32;
    float att[NL];
    #pragma unroll
    for (int t = 0; t < NL; ++t) {
        const int src = sidx[off + l + 32 * t];
        att[t] = dot32(key + src * ld + g * 32, qh) * scale;
    }
    float m = att[0];
    #pragma unroll
    for (int t = 1; t < NL; ++t) m = fmaxf(m, att[t]);
    #pragma unroll
    for (int o = 16; o > 0; o >>= 1) m = fmaxf(m, __shfl_xor(m, o));
    float ex[NL], s = 0.f;
    #pragma unroll
    for (int t = 0; t < NL; ++t) { ex[t] = __expf(att[t] - m); s += ex[t]; }
    #pragma unroll
    for (int o = 16; o > 0; o >>= 1) s += __shfl_xor(s, o);
    const float inv = 1.f / s;
    #pragma unroll
    for (int t = 0; t < NL; ++t) sc[(off + l + 32 * t) * 9 + g] = ex[t] * inv;
}

template <int NE>
__device__ inline void accum_rel(const short* __restrict__ val, int ld,
                                 const int* __restrict__ sidx, int off,
                                 const float* __restrict__ sc,
                                 int es, int ct, int h, float* __restrict__ acc)
{
    #pragma unroll
    for (int e = es; e < NE; e += 8) {
        const float w = sc[(off + e) * 9 + h];
        const uint4 u = *reinterpret_cast<const uint4*>(val + sidx[off + e] * ld + ct * 8);
        acc[0] = fmaf(w, blo(u.x), acc[0]);
        acc[1] = fmaf(w, bhi(u.x), acc[1]);
        acc[2] = fmaf(w, blo(u.y), acc[2]);
        acc[3] = fmaf(w, bhi(u.y), acc[3]);
        acc[4] = fmaf(w, blo(u.z), acc[4]);
        acc[5] = fmaf(w, bhi(u.z), acc[5]);
        acc[6] = fmaf(w, blo(u.w), acc[6]);
        acc[7] = fmaf(w, bhi(u.w), acc[7]);
    }
}

template <int NEA, int NEB>
__global__ __launch_bounds__(256) void msg_k(
    const short* __restrict__ q, int ldq,
    const short* __restrict__ keyA, const short* __restrict__ valA, int ldA,
    const int* __restrict__ srcA,
    const short* __restrict__ keyB, const short* __restrict__ valB, int ldB,
    const int* __restrict__ srcB,
    const float* __restrict__ relPri, int relA, int relB,
    short* __restrict__ out, int n_dst)
{
    constexpr int NET = NEA + NEB;
    const int j = blockIdx.x, tid = threadIdx.x;
    __shared__ float qsh[256];
    __shared__ int sidx[NET];
    __shared__ float sc[NET * 9];
    __shared__ float psA[8][256];
    __shared__ float psB[8][256];

    qsh[tid] = bfu((unsigned short)q[j * ldq + tid]);
    if (tid < NEA) sidx[tid] = srcA[j + tid * n_dst];
    else if (tid < NET) sidx[tid] = srcB[j + (tid - NEA) * n_dst];
    __syncthreads();

    const int g = tid >> 5, l = tid & 31;
    const float* qh = qsh + g * 32;

    if constexpr (NEA == 16 && NEB == 16) {
        const int rel = l >> 4, e = l & 15, off = rel * 16;
        const float scale = relPri[(rel ? relB : relA) * 8 + g] * INV_SQRT_DK;
        const short* key = rel ? keyB : keyA;
        const int ld = rel ? ldB : ldA;
        const float att = dot32(key + sidx[off + e] * ld + g * 32, qh) * scale;
        float m = att;
        #pragma unroll
        for (int o = 8; o > 0; o >>= 1) m = fmaxf(m, __shfl_xor(m, o));
        const float ex = __expf(att - m);
        float s = ex;
        #pragma unroll
        for (int o = 8; o > 0; o >>= 1) s += __shfl_xor(s, o);
        sc[(off + e) * 9 + g] = ex / s;
    } else {
        rel_scores<NEA>(keyA, ldA, sidx, 0,   relPri[relA * 8 + g] * INV_SQRT_DK, qh, sc, g, l);
        rel_scores<NEB>(keyB, ldB, sidx, NEA, relPri[relB * 8 + g] * INV_SQRT_DK, qh, sc, g, l);
    }
    __syncthreads();

    const int es = tid >> 5, ct = tid & 31, hh = ct >> 2;
    float accA[8] = {}, accB[8] = {};
    accum_rel<NEA>(valA, ldA, sidx, 0,   sc, es, ct, hh, accA);
    accum_rel<NEB>(valB, ldB, sidx, NEA, sc, es, ct, hh, accB);
    *reinterpret_cast<float4*>(&psA[es][ct * 8])     = make_float4(accA[0], accA[1], accA[2], accA[3]);
    *reinterpret_cast<float4*>(&psA[es][ct * 8 + 4]) = make_float4(accA[4], accA[5], accA[6], accA[7]);
    *reinterpret_cast<float4*>(&psB[es][ct * 8])     = make_float4(accB[0], accB[1], accB[2], accB[3]);
    *reinterpret_cast<float4*>(&psB[es][ct * 8 + 4]) = make_float4(accB[4], accB[5], accB[6], accB[7]);
    __syncthreads();

    float rA = 0.f, rB = 0.f;
    #pragma unroll
    for (int e2 = 0; e2 < 8; ++e2) { rA += psA[e2][tid]; rB += psB[e2][tid]; }
    out[j * 256 + tid] = f2bf(0.5f * (fmaxf(rA, 0.f) + fmaxf(rB, 0.f)));
}

// =====================================================================
template <bool WB>
__global__ __launch_bounds__(256) void ln_k(
    float* __restrict__ data, const float* __restrict__ g,
    const float* __restrict__ b, int nrows, short* __restrict__ bfout)
{
    const int wid = threadIdx.x >> 6, lane = threadIdx.x & 63;
    const int row = blockIdx.x * 4 + wid;
    if (row >= nrows) return;
    float4 x = *reinterpret_cast<float4*>(data + row * 256 + lane * 4);
    float s  = x.x + x.y + x.z + x.w;
    float q2 = x.x * x.x + x.y * x.y + x.z * x.z + x.w * x.w;
    #pragma unroll
    for (int o = 32; o > 0; o >>= 1) { s += __shfl_xor(s, o); q2 += __shfl_xor(q2, o); }
    const float mu  = s * (1.f / 256.f);
    const float var = q2 * (1.f / 256.f) - mu * mu;
    const float rr = rsqrtf(var + 1e-5f);
    const float4 gg = *reinterpret_cast<const float4*>(g + lane * 4);
    const float4 bb = *reinterpret_cast<const float4*>(b + lane * 4);
    x.x = (x.x - mu) * rr * gg.x + bb.x;
    x.y = (x.y - mu) * rr * gg.y + bb.y;
    x.z = (x.z - mu) * rr * gg.z + bb.z;
    x.w = (x.w - mu) * rr * gg.w + bb.w;
    *reinterpret_cast<float4*>(data + row * 256 + lane * 4) = x;
    if (WB) {
        ushort4 u;
        u.x = (unsigned short)f2bf(x.x); u.y = (unsigned short)f2bf(x.y);
        u.z = (unsigned short)f2bf(x.z); u.w = (unsigned short)f2bf(x.w);
        *reinterpret_cast<ushort4*>((unsigned short*)bfout + row * 256 + lane * 4) = u;
    }
}

// =====================================================================
extern "C" void kernel_launch(void* const* d_in, const int* in_sizes, int n_in,
                              void* d_out, int out_size, void* d_ws, size_t ws_size,
                              hipStream_t stream)
{
    const float* feat_topic = (const float*)d_in[0];
    const float* feat_word  = (const float*)d_in[1];
    const float* feat_doc   = (const float*)d_in[2];
    const float* ht_prev    = (const float*)d_in[3];
    const float* Wk  = (const float*)d_in[4];
    const float* bk  = (const float*)d_in[5];
    const float* Wq  = (const float*)d_in[6];
    const float* bq  = (const float*)d_in[7];
    const float* Wv  = (const float*)d_in[8];
    const float* bv  = (const float*)d_in[9];
    const float* Wa  = (const float*)d_in[10];
    const float* ba  = (const float*)d_in[11];
    const float* ln_g = (const float*)d_in[12];
    const float* ln_b = (const float*)d_in[13];
    const float* skip = (const float*)d_in[14];
    const float* Wih  = (const float*)d_in[15];
    const float* Whh  = (const float*)d_in[16];
    const float* bih  = (const float*)d_in[17];
    const float* bhh  = (const float*)d_in[18];
    const float* rel_pri = (const float*)d_in[19];
    const float* rel_att = (const float*)d_in[20];
    const float* rel_msg = (const float*)d_in[21];
    const int* src_tt = (const int*)d_in[22];
    const int* src_wt = (const int*)d_in[24];
    const int* src_td = (const int*)d_in[26];
    const int* src_wd = (const int*)d_in[28];

    // ---- workspace layout ----
    short* B_t1 = (short*)d_ws;                 // 768*256
    short* B_w  = B_t1 + 196608;                // 1024*256
    short* B_t2 = B_w + 262144;                 // 512*256
    short* Wq2t = B_t2 + 131072;                // 5 x 256*256
    short* Whht = Wq2t + 65536;
    short* Wa0t = Whht + 65536;
    short* Wiht = Wa0t + 65536;
    short* Wa1t = Wiht + 65536;
    short* out1 = Wa1t + 65536;                 // 2000*768   (q_t | key_tt | val_tt)
    short* out2 = out1 + 1536000;               // 50000*1024 (Kwt | Vwt | Kwd | Vwd)
    short* out3 = out2 + 51200000;              // 2000*512   (Ktd | Vtd)
    short* qd   = out3 + 1024000;               // 20000*256
    short* ttop = qd + 5120000;                 // 2000*256
    short* mixb = ttop + 512000;                // 2000*256
    short* tdoc = mixb + 512000;                // 20000*256
    short* xt2  = tdoc + 5120000;               // 2000*256
    float* bias_t1 = (float*)(xt2 + 512000);    // 768
    float* bias_w  = bias_t1 + 768;             // 1024
    float* bias_t2 = bias_w + 1024;             // 512
    float* r2      = bias_t2 + 512;             // 2000*256 fp32

    // wfb: bf16 copy of feat_word (12.8M shorts), ALIASED over
    // [out3..xt2-end] -- all of which are written only AFTER the word
    // GEMM consumes wfb (stream order serializes).
    short* wfb = out3;

    float* out_topic = (float*)d_out;
    float* out_doc   = out_topic + NT * 256;

    // ---- prep: convert feat_word to bf16; fold weights ----
    cvt_bf16<<<dim3(2048), 256, 0, stream>>>(feat_word, wfb, NW * 256 / 8);
    fold_kernel<<<dim3(64), 256, 0, stream>>>(Wk, bk, Wv, bv, rel_att, rel_msg,
                                              B_t1, B_w, B_t2, bias_t1, bias_w, bias_t2);
    TransP tp;
    tp.s[0] = Wq;            tp.d[0] = B_t1;   // Wq[topic]
    tp.s[1] = Wq + 131072;   tp.d[1] = Wq2t;   // Wq[doc]
    tp.s[2] = Whh;           tp.d[2] = Whht;
    tp.s[3] = Wih;           tp.d[3] = Wiht;
    tp.s[4] = Wa;            tp.d[4] = Wa0t;
    tp.s[5] = Wa + 65536;    tp.d[5] = Wa1t;
    wtrans6<<<dim3(256, 6), 256, 0, stream>>>(tp);
    copy_bias<<<dim3(1), 256, 0, stream>>>(bq, bias_t1);

    // ---- word GEMM first (consumes wfb before its alias region is reused) ----
    gemm_lds<false, short, 0, true><<<dim3(8, 392), 256, 0, stream>>>(
        wfb, B_w, bias_w, out2, NW, 1024, nullptr, nullptr, 0);

    // ---- remaining phase-1 projections ----
    gemm_lds<true, short, 0, false><<<dim3(6, 16), 256, 0, stream>>>(
        feat_topic, B_t1, bias_t1, out1, NT, 768, nullptr, nullptr, 0);
    gemm_lds<true, short, 0, false><<<dim3(2, 157), 256, 0, stream>>>(
        feat_doc, Wq2t, bq + 512, qd, ND, 256, nullptr, nullptr, 0);
    gemm_lds<true, float, 0, false><<<dim3(2, 16), 256, 0, stream>>>(
        ht_prev, Whht, bhh, r2, NT, 256, nullptr, nullptr, 0);

    // ---- messages into topic (tt:64/dst, wt:128/dst) ----
    msg_k<64, 128><<<dim3(NT), 256, 0, stream>>>(
        out1, 768,
        out1 + 256, out1 + 512, 768, src_tt,
        out2, out2 + 256, 1024, src_wt,
        rel_pri, 0, 1, ttop, NT);

    // ---- topic update: mix -> RNN tanh -> LN ----
    gemm_lds<false, short, 1, false><<<dim3(2, 16), 256, 0, stream>>>(
        ttop, Wa0t, ba, mixb, NT, 256, feat_topic, skip, 0);
    gemm_lds<false, float, 2, false><<<dim3(2, 16), 256, 0, stream>>>(
        mixb, Wiht, bih, out_topic, NT, 256, r2, nullptr, 0);
    ln_k<true><<<dim3(500), 256, 0, stream>>>(out_topic, ln_g, ln_b, NT, xt2);

    // ---- phase-2 topic projections ----
    gemm_lds<false, short, 0, false><<<dim3(4, 16), 256, 0, stream>>>(
        xt2, B_t2, bias_t2, out3, NT, 512, nullptr, nullptr, 0);

    // ---- messages into doc (td:16/dst, wd:16/dst) ----
    msg_k<16, 16><<<dim3(ND), 256, 0, stream>>>(
        qd, 256,
        out3, out3 + 256, 512, src_td,
        out2 + 512, out2 + 768, 1024, src_wd,
        rel_pri, 2, 3, tdoc, ND);

    // ---- doc update: mix -> LN ----
    gemm_lds<false, float, 1, false><<<dim3(2, 157), 256, 0, stream>>>(
        tdoc, Wa1t, ba + 256, out_doc, ND, 256, feat_doc, skip, 1);
    ln_k<false><<<dim3(5000), 256, 0, stream>>>(out_doc, ln_g + 256, ln_b + 256, ND, nullptr);
}

// Round 6
// 329.346 us; speedup vs baseline: 3.0606x; 1.0708x over previous
//
#include <hip/hip_runtime.h>
#include <hip/hip_bf16.h>
#include <hip/hip_fp8.h>

typedef __attribute__((ext_vector_type(8))) short bf16x8;
typedef __attribute__((ext_vector_type(4))) float f32x4;
typedef __attribute__((ext_vector_type(2))) float f32x2;

constexpr int NT = 2000, NW = 50000, ND = 20000;
constexpr float INV_SQRT_DK = 0.17677669529663687f;  // 1/sqrt(32)

__device__ inline float bfu(unsigned short u) {
    return __uint_as_float(((unsigned int)u) << 16);
}
__device__ inline float blo(unsigned int u) { return __uint_as_float(u << 16); }
__device__ inline float bhi(unsigned int u) { return __uint_as_float(u & 0xffff0000u); }
__device__ inline short f2bf(float x) {
    __hip_bfloat16 h = __float2bfloat16(x);
    short s; __builtin_memcpy(&s, &h, 2); return s;
}

// ---- fp8 e4m3 (OCP) helpers: HW cvt with SW fallback ----
__device__ inline void dec4(unsigned int w, float* o) {
#if __has_builtin(__builtin_amdgcn_cvt_pk_f32_fp8)
    f32x2 a = __builtin_amdgcn_cvt_pk_f32_fp8(w, false);
    f32x2 b = __builtin_amdgcn_cvt_pk_f32_fp8(w, true);
    o[0] = a[0]; o[1] = a[1]; o[2] = b[0]; o[3] = b[1];
#else
    __hip_fp8_e4m3 t0, t1, t2, t3;
    t0.__x = (__hip_fp8_storage_t)(w & 0xff);
    t1.__x = (__hip_fp8_storage_t)((w >> 8) & 0xff);
    t2.__x = (__hip_fp8_storage_t)((w >> 16) & 0xff);
    t3.__x = (__hip_fp8_storage_t)((w >> 24) & 0xff);
    o[0] = (float)t0; o[1] = (float)t1; o[2] = (float)t2; o[3] = (float)t3;
#endif
}
__device__ inline unsigned char f2fp8(float v) {
#if __has_builtin(__builtin_amdgcn_cvt_pk_fp8_f32)
    return (unsigned char)(__builtin_amdgcn_cvt_pk_fp8_f32(v, v, 0u, false) & 0xff);
#else
    __hip_fp8_e4m3 h(v); return (unsigned char)h.__x;
#endif
}

__device__ inline void cstore(float* p, float v) { *p = v; }
__device__ inline void cstore(short* p, float v) { *p = f2bf(v); }
__device__ inline void cstore(unsigned char* p, float v) { *p = f2fp8(v); }

__device__ inline void gload16(const short* g, short* l) {
    __builtin_amdgcn_global_load_lds(
        (const __attribute__((address_space(1))) void*)g,
        (__attribute__((address_space(3))) void*)l, 16, 0, 0);
}

// 32-element bf16 dot with fp32 q (qh group-uniform broadcast from LDS)
__device__ inline float dot32(const short* __restrict__ kp, const float* __restrict__ qh) {
    const uint4* p = reinterpret_cast<const uint4*>(kp);
    float d = 0.f;
    #pragma unroll
    for (int c = 0; c < 4; ++c) {
        const uint4 u = p[c];
        d += qh[c * 8 + 0] * blo(u.x) + qh[c * 8 + 1] * bhi(u.x)
           + qh[c * 8 + 2] * blo(u.y) + qh[c * 8 + 3] * bhi(u.y)
           + qh[c * 8 + 4] * blo(u.z) + qh[c * 8 + 5] * bhi(u.z)
           + qh[c * 8 + 6] * blo(u.w) + qh[c * 8 + 7] * bhi(u.w);
    }
    return d;
}

// 32-element fp8 dot (32 bytes)
__device__ inline float dot32f8(const unsigned char* __restrict__ kp, const float* __restrict__ qh) {
    const uint4 u = *reinterpret_cast<const uint4*>(kp);
    const uint4 v = *reinterpret_cast<const uint4*>(kp + 16);
    const unsigned int ws[8] = {u.x, u.y, u.z, u.w, v.x, v.y, v.z, v.w};
    float d = 0.f;
    #pragma unroll
    for (int c = 0; c < 8; ++c) {
        float f[4];
        dec4(ws[c], f);
        d += qh[c * 4 + 0] * f[0] + qh[c * 4 + 1] * f[1]
           + qh[c * 4 + 2] * f[2] + qh[c * 4 + 3] * f[3];
    }
    return d;
}

// =====================================================================
// fold: per-relation head transforms folded into projection weights,
// written TRANSPOSED bf16 ([n][k]) into the packed B matrices.
// =====================================================================
__global__ __launch_bounds__(256) void fold_kernel(
    const float* __restrict__ Wk, const float* __restrict__ bk,
    const float* __restrict__ Wv, const float* __restrict__ bv,
    const float* __restrict__ rel_att, const float* __restrict__ rel_msg,
    short* __restrict__ B_t1, short* __restrict__ B_w, short* __restrict__ B_t2,
    float* __restrict__ bias_t1, float* __restrict__ bias_w, float* __restrict__ bias_t2)
{
    const int f = blockIdx.x >> 3, chunk = blockIdx.x & 7;
    const int rel = f >> 1, isV = f & 1;
    const int ntype = (rel == 1 || rel == 3) ? 1 : 0;
    const float* Wsrc = (isV ? Wv : Wk) + ntype * 65536;
    const float* bsrc = (isV ? bv : bk) + ntype * 256;
    const float* A    = (isV ? rel_msg : rel_att) + rel * 8192;  // [8][32][32]
    short* wdst; float* bdst;
    switch (f) {
        case 0: wdst = B_t1 + 65536;     bdst = bias_t1 + 256; break;  // K tt
        case 1: wdst = B_t1 + 2 * 65536; bdst = bias_t1 + 512; break;  // V tt
        case 2: wdst = B_w;              bdst = bias_w;        break;  // K wt
        case 3: wdst = B_w + 65536;      bdst = bias_w + 256;  break;  // V wt
        case 4: wdst = B_t2;             bdst = bias_t2;       break;  // K td
        case 5: wdst = B_t2 + 65536;     bdst = bias_t2 + 256; break;  // V td
        case 6: wdst = B_w + 2 * 65536;  bdst = bias_w + 512;  break;  // K wd
        default: wdst = B_w + 3 * 65536; bdst = bias_w + 768;  break;  // V wd
    }
    __shared__ float Wsh[32][256];
    const int tid = threadIdx.x;
    for (int i = 0; i < 32; ++i)
        Wsh[i][tid] = Wsrc[(chunk * 32 + i) * 256 + tid];
    __syncthreads();
    const int h = tid >> 5, o = tid & 31;
    float a[32];
    #pragma unroll
    for (int d = 0; d < 32; ++d) a[d] = A[h * 1024 + d * 32 + o];
    short tmp[32];
    #pragma unroll
    for (int r = 0; r < 32; ++r) {
        float s = 0.f;
        #pragma unroll
        for (int d = 0; d < 32; ++d) s = fmaf(Wsh[r][(h << 5) + d], a[d], s);
        tmp[r] = f2bf(s);
    }
    short* wp = wdst + tid * 256 + chunk * 32;
    #pragma unroll
    for (int r8 = 0; r8 < 4; ++r8) {
        bf16x8 v;
        #pragma unroll
        for (int t = 0; t < 8; ++t) v[t] = tmp[r8 * 8 + t];
        *reinterpret_cast<bf16x8*>(wp + r8 * 8) = v;
    }
    if (chunk == 0) {
        float s = 0.f;
        #pragma unroll
        for (int d = 0; d < 32; ++d) s = fmaf(bsrc[(h << 5) + d], a[d], s);
        bdst[tid] = s;
    }
}

struct TransP { const float* s[6]; short* d[6]; };
__global__ __launch_bounds__(256) void wtrans6(TransP p) {
    const int m = blockIdx.y, n = blockIdx.x, k = threadIdx.x;
    p.d[m][n * 256 + k] = f2bf(p.s[m][k * 256 + n]);
}

__global__ void copy_bias(const float* __restrict__ s, float* __restrict__ d) {
    d[threadIdx.x] = s[threadIdx.x];
}

// =====================================================================
// fp32 -> bf16 convert (vectorized, grid-stride); n8 = count/8
// =====================================================================
__global__ __launch_bounds__(256) void cvt_bf16(
    const float* __restrict__ src, short* __restrict__ dst, int n8)
{
    const int stride = gridDim.x * 256;
    for (int i = blockIdx.x * 256 + threadIdx.x; i < n8; i += stride) {
        const float* p = src + (long)i * 8;
        const float4 x0 = *reinterpret_cast<const float4*>(p);
        const float4 x1 = *reinterpret_cast<const float4*>(p + 4);
        bf16x8 v;
        v[0] = f2bf(x0.x); v[1] = f2bf(x0.y); v[2] = f2bf(x0.z); v[3] = f2bf(x0.w);
        v[4] = f2bf(x1.x); v[5] = f2bf(x1.y); v[6] = f2bf(x1.z); v[7] = f2bf(x1.w);
        *reinterpret_cast<bf16x8*>(dst + (long)i * 8) = v;
    }
}

// =====================================================================
// LDS-staged MFMA GEMM (m97 structure) with optional XCD-colocating
// block swizzle (SWZ=true; grid (8, rows padded to x8)).
// =====================================================================
template <bool XF32, typename OutT, int EPI, bool SWZ>
__global__ __launch_bounds__(256) void gemm_lds(
    const void* __restrict__ Xv, const short* __restrict__ Wt,
    const float* __restrict__ bias, OutT* __restrict__ C,
    int M, int ldc, const float* __restrict__ extra,
    const float* __restrict__ skipv, int skipIdx)
{
    __shared__ short As[128 * 64];
    __shared__ short Bs[128 * 64];
    int bxi = blockIdx.x, byi = blockIdx.y;
    if constexpr (SWZ) {
        const int h = bxi + (int)gridDim.x * byi;
        const int i = h >> 3;
        byi = (h & 7) + 8 * (i >> 3);
        bxi = i & 7;
        if (byi * 128 >= M) return;
    }
    const int tid = threadIdx.x;
    const int wave = tid >> 6, lane = tid & 63;
    const int wm = wave >> 1, wn = wave & 1;
    const int r = lane & 15, kb = lane >> 4;
    const int col0 = bxi * 128;
    const int row0 = byi * 128;

    const int l8 = lane >> 3;
    const int c8 = lane & 7;
    const int swz8 = c8 ^ l8;
    f32x4 acc[4][4] = {};

    for (int k0 = 0; k0 < 256; k0 += 64) {
        if (k0) __syncthreads();
        if constexpr (XF32) {
            #pragma unroll
            for (int q = 0; q < 4; ++q) {
                const int rl = wave * 32 + q * 8 + l8;
                const int grow = min(row0 + rl, M - 1);
                const float* xp = (const float*)Xv + grow * 256 + k0 + c8 * 8;
                const float4 x0 = *reinterpret_cast<const float4*>(xp);
                const float4 x1 = *reinterpret_cast<const float4*>(xp + 4);
                bf16x8 v;
                v[0] = f2bf(x0.x); v[1] = f2bf(x0.y); v[2] = f2bf(x0.z); v[3] = f2bf(x0.w);
                v[4] = f2bf(x1.x); v[5] = f2bf(x1.y); v[6] = f2bf(x1.z); v[7] = f2bf(x1.w);
                *reinterpret_cast<bf16x8*>(As + rl * 64 + swz8 * 8) = v;
            }
        } else {
            #pragma unroll
            for (int q = 0; q < 4; ++q) {
                const int rl = wave * 32 + q * 8 + l8;
                const int grow = min(row0 + rl, M - 1);
                gload16((const short*)Xv + grow * 256 + k0 + swz8 * 8,
                        As + (wave * 32 + q * 8) * 64);
            }
        }
        #pragma unroll
        for (int q = 0; q < 4; ++q) {
            const int cl = wave * 32 + q * 8 + l8;
            gload16(Wt + (col0 + cl) * 256 + k0 + swz8 * 8,
                    Bs + (wave * 32 + q * 8) * 64);
        }
        __syncthreads();
        #pragma unroll
        for (int s = 0; s < 2; ++s) {
            const int csw = ((kb + 4 * s) ^ (r & 7)) * 8;
            bf16x8 af[4], bw[4];
            #pragma unroll
            for (int i = 0; i < 4; ++i) {
                af[i] = *reinterpret_cast<const bf16x8*>(As + (wm * 64 + i * 16 + r) * 64 + csw);
                bw[i] = *reinterpret_cast<const bf16x8*>(Bs + (wn * 64 + i * 16 + r) * 64 + csw);
            }
            #pragma unroll
            for (int i = 0; i < 4; ++i)
                #pragma unroll
                for (int j = 0; j < 4; ++j)
                    acc[i][j] = __builtin_amdgcn_mfma_f32_16x16x32_bf16(af[i], bw[j], acc[i][j], 0, 0, 0);
        }
    }

    float alpha = 0.f;
    if (EPI == 1) alpha = 1.f / (1.f + __expf(-skipv[skipIdx]));
    #pragma unroll
    for (int i = 0; i < 4; ++i) {
        #pragma unroll
        for (int j = 0; j < 4; ++j) {
            const int col = col0 + wn * 64 + j * 16 + r;
            const float bc = bias[col];
            #pragma unroll
            for (int t = 0; t < 4; ++t) {
                const int rrow = row0 + wm * 64 + i * 16 + kb * 4 + t;
                if (rrow < M) {
                    float v = acc[i][j][t] + bc;
                    if (EPI == 1) v = alpha * v + (1.f - alpha) * extra[rrow * 256 + col];
                    if (EPI == 2) v = tanhf(v + extra[rrow * 256 + col]);
                    cstore(C + rrow * ldc + col, v);
                }
            }
        }
    }
}

// =====================================================================
// msg_k: relation A = bf16 K/V, relation B = fp8 K/V (word panels).
// Per-head score groups, register softmax (pre-divided), 8-slot
// accumulate (A: 16B bf16 loads, B: 8B fp8 loads), swizzled LDS reduce.
// =====================================================================
template <int NE>
__device__ inline void rel_scores(const short* __restrict__ key, int ld,
                                  const int* __restrict__ sidx, int off, float scale,
                                  const float* __restrict__ qh, float* __restrict__ sc,
                                  int g, int l)
{
    constexpr int NL = NE / 32;
    float att[NL];
    #pragma unroll
    for (int t = 0; t < NL; ++t)
        att[t] = dot32(key + sidx[off + l + 32 * t] * ld + g * 32, qh) * scale;
    float m = att[0];
    #pragma unroll
    for (int t = 1; t < NL; ++t) m = fmaxf(m, att[t]);
    #pragma unroll
    for (int o = 16; o > 0; o >>= 1) m = fmaxf(m, __shfl_xor(m, o));
    float ex[NL], s = 0.f;
    #pragma unroll
    for (int t = 0; t < NL; ++t) { ex[t] = __expf(att[t] - m); s += ex[t]; }
    #pragma unroll
    for (int o = 16; o > 0; o >>= 1) s += __shfl_xor(s, o);
    const float inv = 1.f / s;
    #pragma unroll
    for (int t = 0; t < NL; ++t) sc[(off + l + 32 * t) * 9 + g] = ex[t] * inv;
}

template <int NE>
__device__ inline void rel_scores_f8(const unsigned char* __restrict__ kv, int ld, int koff,
                                     const int* __restrict__ sidx, int off, float scale,
                                     const float* __restrict__ qh, float* __restrict__ sc,
                                     int g, int l)
{
    constexpr int NL = NE / 32;
    float att[NL];
    #pragma unroll
    for (int t = 0; t < NL; ++t)
        att[t] = dot32f8(kv + (size_t)sidx[off + l + 32 * t] * ld + koff + g * 32, qh) * scale;
    float m = att[0];
    #pragma unroll
    for (int t = 1; t < NL; ++t) m = fmaxf(m, att[t]);
    #pragma unroll
    for (int o = 16; o > 0; o >>= 1) m = fmaxf(m, __shfl_xor(m, o));
    float ex[NL], s = 0.f;
    #pragma unroll
    for (int t = 0; t < NL; ++t) { ex[t] = __expf(att[t] - m); s += ex[t]; }
    #pragma unroll
    for (int o = 16; o > 0; o >>= 1) s += __shfl_xor(s, o);
    const float inv = 1.f / s;
    #pragma unroll
    for (int t = 0; t < NL; ++t) sc[(off + l + 32 * t) * 9 + g] = ex[t] * inv;
}

template <int NE>
__device__ inline void accum_rel(const short* __restrict__ val, int ld,
                                 const int* __restrict__ sidx, int off,
                                 const float* __restrict__ sc,
                                 int es, int ct, int h, float* __restrict__ acc)
{
    #pragma unroll
    for (int e = es; e < NE; e += 8) {
        const float w = sc[(off + e) * 9 + h];
        const uint4 u = *reinterpret_cast<const uint4*>(val + sidx[off + e] * ld + ct * 8);
        acc[0] = fmaf(w, blo(u.x), acc[0]);
        acc[1] = fmaf(w, bhi(u.x), acc[1]);
        acc[2] = fmaf(w, blo(u.y), acc[2]);
        acc[3] = fmaf(w, bhi(u.y), acc[3]);
        acc[4] = fmaf(w, blo(u.z), acc[4]);
        acc[5] = fmaf(w, bhi(u.z), acc[5]);
        acc[6] = fmaf(w, blo(u.w), acc[6]);
        acc[7] = fmaf(w, bhi(u.w), acc[7]);
    }
}

template <int NE>
__device__ inline void accum_f8(const unsigned char* __restrict__ kv, int ld, int voff,
                                const int* __restrict__ sidx, int off,
                                const float* __restrict__ sc,
                                int es, int ct, int h, float* __restrict__ acc)
{
    #pragma unroll
    for (int e = es; e < NE; e += 8) {
        const float w = sc[(off + e) * 9 + h];
        const uint2 u = *reinterpret_cast<const uint2*>(
            kv + (size_t)sidx[off + e] * ld + voff + ct * 8);
        float f[8];
        dec4(u.x, f); dec4(u.y, f + 4);
        #pragma unroll
        for (int k = 0; k < 8; ++k) acc[k] = fmaf(w, f[k], acc[k]);
    }
}

template <int NEA, int NEB>
__global__ __launch_bounds__(256) void msg_k(
    const short* __restrict__ q, int ldq,
    const short* __restrict__ keyA, const short* __restrict__ valA, int ldA,
    const int* __restrict__ srcA,
    const unsigned char* __restrict__ kvB, int ldB, int koffB, int voffB,
    const int* __restrict__ srcB,
    const float* __restrict__ relPri, int relA, int relB,
    short* __restrict__ out, int n_dst)
{
    constexpr int NET = NEA + NEB;
    const int j = blockIdx.x, tid = threadIdx.x;
    __shared__ float qsh[256];
    __shared__ int sidx[NET];
    __shared__ float sc[NET * 9];
    __shared__ float psA[8][256];
    __shared__ float psB[8][256];

    qsh[tid] = bfu((unsigned short)q[j * ldq + tid]);
    if (tid < NEA) sidx[tid] = srcA[j + tid * n_dst];
    else if (tid < NET) sidx[tid] = srcB[j + (tid - NEA) * n_dst];
    __syncthreads();

    const int g = tid >> 5, l = tid & 31;
    const float* qh = qsh + g * 32;

    if constexpr (NEA == 16 && NEB == 16) {
        // doc: 16-lane redundant compute in each half, no divergence
        {
            const int e = l & 15;
            const float scale = relPri[relA * 8 + g] * INV_SQRT_DK;
            const float att = dot32(keyA + sidx[e] * ldA + g * 32, qh) * scale;
            float m = att;
            #pragma unroll
            for (int o = 8; o > 0; o >>= 1) m = fmaxf(m, __shfl_xor(m, o));
            const float ex = __expf(att - m);
            float s = ex;
            #pragma unroll
            for (int o = 8; o > 0; o >>= 1) s += __shfl_xor(s, o);
            if (l < 16) sc[e * 9 + g] = ex / s;
        }
        {
            const int e = l & 15;
            const float scale = relPri[relB * 8 + g] * INV_SQRT_DK;
            const float att = dot32f8(kvB + (size_t)sidx[16 + e] * ldB + koffB + g * 32, qh) * scale;
            float m = att;
            #pragma unroll
            for (int o = 8; o > 0; o >>= 1) m = fmaxf(m, __shfl_xor(m, o));
            const float ex = __expf(att - m);
            float s = ex;
            #pragma unroll
            for (int o = 8; o > 0; o >>= 1) s += __shfl_xor(s, o);
            if (l < 16) sc[(16 + e) * 9 + g] = ex / s;
        }
    } else {
        rel_scores<NEA>(keyA, ldA, sidx, 0, relPri[relA * 8 + g] * INV_SQRT_DK, qh, sc, g, l);
        rel_scores_f8<NEB>(kvB, ldB, koffB, sidx, NEA, relPri[relB * 8 + g] * INV_SQRT_DK, qh, sc, g, l);
    }
    __syncthreads();

    const int es = tid >> 5, ct = tid & 31, hh = ct >> 2;
    float accA[8] = {}, accB[8] = {};
    accum_rel<NEA>(valA, ldA, sidx, 0, sc, es, ct, hh, accA);
    accum_f8<NEB>(kvB, ldB, voffB, sidx, NEA, sc, es, ct, hh, accB);
    // swizzled ps writes: value for col c stored at c ^ ((c>>3)&4)
    const int sw = ct & 4;
    *reinterpret_cast<float4*>(&psA[es][(ct * 8) ^ sw])     = make_float4(accA[0], accA[1], accA[2], accA[3]);
    *reinterpret_cast<float4*>(&psA[es][(ct * 8 + 4) ^ sw]) = make_float4(accA[4], accA[5], accA[6], accA[7]);
    *reinterpret_cast<float4*>(&psB[es][(ct * 8) ^ sw])     = make_float4(accB[0], accB[1], accB[2], accB[3]);
    *reinterpret_cast<float4*>(&psB[es][(ct * 8 + 4) ^ sw]) = make_float4(accB[4], accB[5], accB[6], accB[7]);
    __syncthreads();

    float rA = 0.f, rB = 0.f;
    const int rp = tid ^ ((tid >> 3) & 4);
    #pragma unroll
    for (int e2 = 0; e2 < 8; ++e2) { rA += psA[e2][rp]; rB += psB[e2][rp]; }
    out[j * 256 + tid] = f2bf(0.5f * (fmaxf(rA, 0.f) + fmaxf(rB, 0.f)));
}

// =====================================================================
template <bool WB>
__global__ __launch_bounds__(256) void ln_k(
    float* __restrict__ data, const float* __restrict__ g,
    const float* __restrict__ b, int nrows, short* __restrict__ bfout)
{
    const int wid = threadIdx.x >> 6, lane = threadIdx.x & 63;
    const int row = blockIdx.x * 4 + wid;
    if (row >= nrows) return;
    float4 x = *reinterpret_cast<float4*>(data + row * 256 + lane * 4);
    float s  = x.x + x.y + x.z + x.w;
    float q2 = x.x * x.x + x.y * x.y + x.z * x.z + x.w * x.w;
    #pragma unroll
    for (int o = 32; o > 0; o >>= 1) { s += __shfl_xor(s, o); q2 += __shfl_xor(q2, o); }
    const float mu  = s * (1.f / 256.f);
    const float var = q2 * (1.f / 256.f) - mu * mu;
    const float rr = rsqrtf(var + 1e-5f);
    const float4 gg = *reinterpret_cast<const float4*>(g + lane * 4);
    const float4 bb = *reinterpret_cast<const float4*>(b + lane * 4);
    x.x = (x.x - mu) * rr * gg.x + bb.x;
    x.y = (x.y - mu) * rr * gg.y + bb.y;
    x.z = (x.z - mu) * rr * gg.z + bb.z;
    x.w = (x.w - mu) * rr * gg.w + bb.w;
    *reinterpret_cast<float4*>(data + row * 256 + lane * 4) = x;
    if (WB) {
        ushort4 u;
        u.x = (unsigned short)f2bf(x.x); u.y = (unsigned short)f2bf(x.y);
        u.z = (unsigned short)f2bf(x.z); u.w = (unsigned short)f2bf(x.w);
        *reinterpret_cast<ushort4*>((unsigned short*)bfout + row * 256 + lane * 4) = u;
    }
}

// =====================================================================
extern "C" void kernel_launch(void* const* d_in, const int* in_sizes, int n_in,
                              void* d_out, int out_size, void* d_ws, size_t ws_size,
                              hipStream_t stream)
{
    const float* feat_topic = (const float*)d_in[0];
    const float* feat_word  = (const float*)d_in[1];
    const float* feat_doc   = (const float*)d_in[2];
    const float* ht_prev    = (const float*)d_in[3];
    const float* Wk  = (const float*)d_in[4];
    const float* bk  = (const float*)d_in[5];
    const float* Wq  = (const float*)d_in[6];
    const float* bq  = (const float*)d_in[7];
    const float* Wv  = (const float*)d_in[8];
    const float* bv  = (const float*)d_in[9];
    const float* Wa  = (const float*)d_in[10];
    const float* ba  = (const float*)d_in[11];
    const float* ln_g = (const float*)d_in[12];
    const float* ln_b = (const float*)d_in[13];
    const float* skip = (const float*)d_in[14];
    const float* Wih  = (const float*)d_in[15];
    const float* Whh  = (const float*)d_in[16];
    const float* bih  = (const float*)d_in[17];
    const float* bhh  = (const float*)d_in[18];
    const float* rel_pri = (const float*)d_in[19];
    const float* rel_att = (const float*)d_in[20];
    const float* rel_msg = (const float*)d_in[21];
    const int* src_tt = (const int*)d_in[22];
    const int* src_wt = (const int*)d_in[24];
    const int* src_td = (const int*)d_in[26];
    const int* src_wd = (const int*)d_in[28];

    // ---- workspace layout (offsets in shorts, unchanged) ----
    short* B_t1 = (short*)d_ws;                 // 768*256
    short* B_w  = B_t1 + 196608;                // 1024*256
    short* B_t2 = B_w + 262144;                 // 512*256
    short* Wq2t = B_t2 + 131072;                // 5 x 256*256
    short* Whht = Wq2t + 65536;
    short* Wa0t = Whht + 65536;
    short* Wiht = Wa0t + 65536;
    short* Wa1t = Wiht + 65536;
    short* out1 = Wa1t + 65536;                 // 2000*768   (q_t | K_tt | V_tt) bf16
    short* out2 = out1 + 1536000;               // word K/V fp8: [50000][1024] uchar
    short* out3 = out2 + 51200000;              // 2000*512   (K_td | V_td) bf16
    short* qd   = out3 + 1024000;               // 20000*256
    short* ttop = qd + 5120000;                 // 2000*256
    short* mixb = ttop + 512000;                // 2000*256
    short* tdoc = mixb + 512000;                // 20000*256
    short* xt2  = tdoc + 5120000;               // 2000*256
    float* bias_t1 = (float*)(xt2 + 512000);    // 768
    float* bias_w  = bias_t1 + 768;             // 1024
    float* bias_t2 = bias_w + 1024;             // 512
    float* r2      = bias_t2 + 512;             // 2000*256 fp32

    unsigned char* w8 = (unsigned char*)out2;   // fp8 panels: Kwt|Vwt|Kwd|Vwd, ld=1024B

    // wfb: bf16 copy of feat_word (12.8M shorts), ALIASED over
    // [out3..xt2-end] -- all written only AFTER the word GEMM consumes wfb.
    short* wfb = out3;

    float* out_topic = (float*)d_out;
    float* out_doc   = out_topic + NT * 256;

    // ---- prep: convert feat_word to bf16; fold weights ----
    cvt_bf16<<<dim3(2048), 256, 0, stream>>>(feat_word, wfb, NW * 256 / 8);
    fold_kernel<<<dim3(64), 256, 0, stream>>>(Wk, bk, Wv, bv, rel_att, rel_msg,
                                              B_t1, B_w, B_t2, bias_t1, bias_w, bias_t2);
    TransP tp;
    tp.s[0] = Wq;            tp.d[0] = B_t1;   // Wq[topic]
    tp.s[1] = Wq + 131072;   tp.d[1] = Wq2t;   // Wq[doc]
    tp.s[2] = Whh;           tp.d[2] = Whht;
    tp.s[3] = Wih;           tp.d[3] = Wiht;
    tp.s[4] = Wa;            tp.d[4] = Wa0t;
    tp.s[5] = Wa + 65536;    tp.d[5] = Wa1t;
    wtrans6<<<dim3(256, 6), 256, 0, stream>>>(tp);
    copy_bias<<<dim3(1), 256, 0, stream>>>(bq, bias_t1);

    // ---- word GEMM first (fp8 output; consumes wfb before alias reuse) ----
    gemm_lds<false, unsigned char, 0, true><<<dim3(8, 392), 256, 0, stream>>>(
        wfb, B_w, bias_w, w8, NW, 1024, nullptr, nullptr, 0);

    // ---- remaining phase-1 projections ----
    gemm_lds<true, short, 0, false><<<dim3(6, 16), 256, 0, stream>>>(
        feat_topic, B_t1, bias_t1, out1, NT, 768, nullptr, nullptr, 0);
    gemm_lds<true, short, 0, false><<<dim3(2, 157), 256, 0, stream>>>(
        feat_doc, Wq2t, bq + 512, qd, ND, 256, nullptr, nullptr, 0);
    gemm_lds<true, float, 0, false><<<dim3(2, 16), 256, 0, stream>>>(
        ht_prev, Whht, bhh, r2, NT, 256, nullptr, nullptr, 0);

    // ---- messages into topic (tt:64/dst bf16, wt:128/dst fp8) ----
    msg_k<64, 128><<<dim3(NT), 256, 0, stream>>>(
        out1, 768,
        out1 + 256, out1 + 512, 768, src_tt,
        w8, 1024, 0, 256, src_wt,
        rel_pri, 0, 1, ttop, NT);

    // ---- topic update: mix -> RNN tanh -> LN ----
    gemm_lds<false, short, 1, false><<<dim3(2, 16), 256, 0, stream>>>(
        ttop, Wa0t, ba, mixb, NT, 256, feat_topic, skip, 0);
    gemm_lds<false, float, 2, false><<<dim3(2, 16), 256, 0, stream>>>(
        mixb, Wiht, bih, out_topic, NT, 256, r2, nullptr, 0);
    ln_k<true><<<dim3(500), 256, 0, stream>>>(out_topic, ln_g, ln_b, NT, xt2);

    // ---- phase-2 topic projections ----
    gemm_lds<false, short, 0, false><<<dim3(4, 16), 256, 0, stream>>>(
        xt2, B_t2, bias_t2, out3, NT, 512, nullptr, nullptr, 0);

    // ---- messages into doc (td:16/dst bf16, wd:16/dst fp8) ----
    msg_k<16, 16><<<dim3(ND), 256, 0, stream>>>(
        qd, 256,
        out3, out3 + 256, 512, src_td,
        w8, 1024, 512, 768, src_wd,
        rel_pri, 2, 3, tdoc, ND);

    // ---- doc update: mix -> LN ----
    gemm_lds<false, float, 1, false><<<dim3(2, 157), 256, 0, stream>>>(
        tdoc, Wa1t, ba + 256, out_doc, ND, 256, feat_doc, skip, 1);
    ln_k<false><<<dim3(5000), 256, 0, stream>>>(out_doc, ln_g + 256, ln_b + 256, ND, nullptr);
}

// Round 7
// 311.562 us; speedup vs baseline: 3.2353x; 1.0571x over previous
//
#include <hip/hip_runtime.h>
#include <hip/hip_bf16.h>
#include <hip/hip_fp8.h>

typedef __attribute__((ext_vector_type(8))) short bf16x8;
typedef __attribute__((ext_vector_type(4))) float f32x4;
typedef __attribute__((ext_vector_type(2))) float f32x2;

constexpr int NT = 2000, NW = 50000, ND = 20000;
constexpr float INV_SQRT_DK = 0.17677669529663687f;  // 1/sqrt(32)

__device__ inline float bfu(unsigned short u) {
    return __uint_as_float(((unsigned int)u) << 16);
}
__device__ inline float blo(unsigned int u) { return __uint_as_float(u << 16); }
__device__ inline float bhi(unsigned int u) { return __uint_as_float(u & 0xffff0000u); }
__device__ inline short f2bf(float x) {
    __hip_bfloat16 h = __float2bfloat16(x);
    short s; __builtin_memcpy(&s, &h, 2); return s;
}

// ---- fp8 e4m3 (OCP) helpers: HW cvt with SW fallback ----
__device__ inline void dec4(unsigned int w, float* o) {
#if __has_builtin(__builtin_amdgcn_cvt_pk_f32_fp8)
    f32x2 a = __builtin_amdgcn_cvt_pk_f32_fp8(w, false);
    f32x2 b = __builtin_amdgcn_cvt_pk_f32_fp8(w, true);
    o[0] = a[0]; o[1] = a[1]; o[2] = b[0]; o[3] = b[1];
#else
    __hip_fp8_e4m3 t0, t1, t2, t3;
    t0.__x = (__hip_fp8_storage_t)(w & 0xff);
    t1.__x = (__hip_fp8_storage_t)((w >> 8) & 0xff);
    t2.__x = (__hip_fp8_storage_t)((w >> 16) & 0xff);
    t3.__x = (__hip_fp8_storage_t)((w >> 24) & 0xff);
    o[0] = (float)t0; o[1] = (float)t1; o[2] = (float)t2; o[3] = (float)t3;
#endif
}
__device__ inline unsigned char f2fp8(float v) {
#if __has_builtin(__builtin_amdgcn_cvt_pk_fp8_f32)
    return (unsigned char)(__builtin_amdgcn_cvt_pk_fp8_f32(v, v, 0u, false) & 0xff);
#else
    __hip_fp8_e4m3 h(v); return (unsigned char)h.__x;
#endif
}

__device__ inline void cstore(float* p, float v) { *p = v; }
__device__ inline void cstore(short* p, float v) { *p = f2bf(v); }
__device__ inline void cstore(unsigned char* p, float v) { *p = f2fp8(v); }

__device__ inline void gload16(const short* g, short* l) {
    __builtin_amdgcn_global_load_lds(
        (const __attribute__((address_space(1))) void*)g,
        (__attribute__((address_space(3))) void*)l, 16, 0, 0);
}

// 32-element fp8 dot against fp32 q in registers
__device__ inline float dot32f8(const unsigned char* __restrict__ kp, const float* __restrict__ qh) {
    const uint4 u = *reinterpret_cast<const uint4*>(kp);
    const uint4 v = *reinterpret_cast<const uint4*>(kp + 16);
    const unsigned int ws[8] = {u.x, u.y, u.z, u.w, v.x, v.y, v.z, v.w};
    float d = 0.f;
    #pragma unroll
    for (int c = 0; c < 8; ++c) {
        float f[4];
        dec4(ws[c], f);
        d += qh[c * 4 + 0] * f[0] + qh[c * 4 + 1] * f[1]
           + qh[c * 4 + 2] * f[2] + qh[c * 4 + 3] * f[3];
    }
    return d;
}

// =====================================================================
// fold: per-relation head transforms folded into projection weights,
// written TRANSPOSED bf16 ([n][k]) into the packed B matrices.
// =====================================================================
__global__ __launch_bounds__(256) void fold_kernel(
    const float* __restrict__ Wk, const float* __restrict__ bk,
    const float* __restrict__ Wv, const float* __restrict__ bv,
    const float* __restrict__ rel_att, const float* __restrict__ rel_msg,
    short* __restrict__ B_t1, short* __restrict__ B_w, short* __restrict__ B_t2,
    float* __restrict__ bias_t1, float* __restrict__ bias_w, float* __restrict__ bias_t2)
{
    const int f = blockIdx.x >> 3, chunk = blockIdx.x & 7;
    const int rel = f >> 1, isV = f & 1;
    const int ntype = (rel == 1 || rel == 3) ? 1 : 0;
    const float* Wsrc = (isV ? Wv : Wk) + ntype * 65536;
    const float* bsrc = (isV ? bv : bk) + ntype * 256;
    const float* A    = (isV ? rel_msg : rel_att) + rel * 8192;  // [8][32][32]
    short* wdst; float* bdst;
    switch (f) {
        case 0: wdst = B_t1 + 65536;     bdst = bias_t1 + 256; break;  // K tt
        case 1: wdst = B_t1 + 2 * 65536; bdst = bias_t1 + 512; break;  // V tt
        case 2: wdst = B_w;              bdst = bias_w;        break;  // K wt
        case 3: wdst = B_w + 65536;      bdst = bias_w + 256;  break;  // V wt
        case 4: wdst = B_t2;             bdst = bias_t2;       break;  // K td
        case 5: wdst = B_t2 + 65536;     bdst = bias_t2 + 256; break;  // V td
        case 6: wdst = B_w + 2 * 65536;  bdst = bias_w + 512;  break;  // K wd
        default: wdst = B_w + 3 * 65536; bdst = bias_w + 768;  break;  // V wd
    }
    __shared__ float Wsh[32][256];
    const int tid = threadIdx.x;
    for (int i = 0; i < 32; ++i)
        Wsh[i][tid] = Wsrc[(chunk * 32 + i) * 256 + tid];
    __syncthreads();
    const int h = tid >> 5, o = tid & 31;
    float a[32];
    #pragma unroll
    for (int d = 0; d < 32; ++d) a[d] = A[h * 1024 + d * 32 + o];
    short tmp[32];
    #pragma unroll
    for (int r = 0; r < 32; ++r) {
        float s = 0.f;
        #pragma unroll
        for (int d = 0; d < 32; ++d) s = fmaf(Wsh[r][(h << 5) + d], a[d], s);
        tmp[r] = f2bf(s);
    }
    short* wp = wdst + tid * 256 + chunk * 32;
    #pragma unroll
    for (int r8 = 0; r8 < 4; ++r8) {
        bf16x8 v;
        #pragma unroll
        for (int t = 0; t < 8; ++t) v[t] = tmp[r8 * 8 + t];
        *reinterpret_cast<bf16x8*>(wp + r8 * 8) = v;
    }
    if (chunk == 0) {
        float s = 0.f;
        #pragma unroll
        for (int d = 0; d < 32; ++d) s = fmaf(bsrc[(h << 5) + d], a[d], s);
        bdst[tid] = s;
    }
}

struct TransP { const float* s[6]; short* d[6]; };
__global__ __launch_bounds__(256) void wtrans6(TransP p) {
    const int m = blockIdx.y, n = blockIdx.x, k = threadIdx.x;
    p.d[m][n * 256 + k] = f2bf(p.s[m][k * 256 + n]);
}

__global__ void copy_bias(const float* __restrict__ s, float* __restrict__ d) {
    d[threadIdx.x] = s[threadIdx.x];
}

// =====================================================================
// LDS-staged MFMA GEMM (m97 structure) with optional XCD-colocating
// block swizzle (SWZ=true; grid (8, rows padded to x8)).
// =====================================================================
template <bool XF32, typename OutT, int EPI, bool SWZ>
__global__ __launch_bounds__(256) void gemm_lds(
    const void* __restrict__ Xv, const short* __restrict__ Wt,
    const float* __restrict__ bias, OutT* __restrict__ C,
    int M, int ldc, const float* __restrict__ extra,
    const float* __restrict__ skipv, int skipIdx)
{
    __shared__ short As[128 * 64];
    __shared__ short Bs[128 * 64];
    int bxi = blockIdx.x, byi = blockIdx.y;
    if constexpr (SWZ) {
        const int h = bxi + (int)gridDim.x * byi;
        const int i = h >> 3;
        byi = (h & 7) + 8 * (i >> 3);
        bxi = i & 7;
        if (byi * 128 >= M) return;
    }
    const int tid = threadIdx.x;
    const int wave = tid >> 6, lane = tid & 63;
    const int wm = wave >> 1, wn = wave & 1;
    const int r = lane & 15, kb = lane >> 4;
    const int col0 = bxi * 128;
    const int row0 = byi * 128;

    const int l8 = lane >> 3;
    const int c8 = lane & 7;
    const int swz8 = c8 ^ l8;
    f32x4 acc[4][4] = {};

    for (int k0 = 0; k0 < 256; k0 += 64) {
        if (k0) __syncthreads();
        if constexpr (XF32) {
            #pragma unroll
            for (int q = 0; q < 4; ++q) {
                const int rl = wave * 32 + q * 8 + l8;
                const int grow = min(row0 + rl, M - 1);
                const float* xp = (const float*)Xv + grow * 256 + k0 + c8 * 8;
                const float4 x0 = *reinterpret_cast<const float4*>(xp);
                const float4 x1 = *reinterpret_cast<const float4*>(xp + 4);
                bf16x8 v;
                v[0] = f2bf(x0.x); v[1] = f2bf(x0.y); v[2] = f2bf(x0.z); v[3] = f2bf(x0.w);
                v[4] = f2bf(x1.x); v[5] = f2bf(x1.y); v[6] = f2bf(x1.z); v[7] = f2bf(x1.w);
                *reinterpret_cast<bf16x8*>(As + rl * 64 + swz8 * 8) = v;
            }
        } else {
            #pragma unroll
            for (int q = 0; q < 4; ++q) {
                const int rl = wave * 32 + q * 8 + l8;
                const int grow = min(row0 + rl, M - 1);
                gload16((const short*)Xv + grow * 256 + k0 + swz8 * 8,
                        As + (wave * 32 + q * 8) * 64);
            }
        }
        #pragma unroll
        for (int q = 0; q < 4; ++q) {
            const int cl = wave * 32 + q * 8 + l8;
            gload16(Wt + (col0 + cl) * 256 + k0 + swz8 * 8,
                    Bs + (wave * 32 + q * 8) * 64);
        }
        __syncthreads();
        #pragma unroll
        for (int s = 0; s < 2; ++s) {
            const int csw = ((kb + 4 * s) ^ (r & 7)) * 8;
            bf16x8 af[4], bw[4];
            #pragma unroll
            for (int i = 0; i < 4; ++i) {
                af[i] = *reinterpret_cast<const bf16x8*>(As + (wm * 64 + i * 16 + r) * 64 + csw);
                bw[i] = *reinterpret_cast<const bf16x8*>(Bs + (wn * 64 + i * 16 + r) * 64 + csw);
            }
            #pragma unroll
            for (int i = 0; i < 4; ++i)
                #pragma unroll
                for (int j = 0; j < 4; ++j)
                    acc[i][j] = __builtin_amdgcn_mfma_f32_16x16x32_bf16(af[i], bw[j], acc[i][j], 0, 0, 0);
        }
    }

    float alpha = 0.f;
    if (EPI == 1) alpha = 1.f / (1.f + __expf(-skipv[skipIdx]));
    #pragma unroll
    for (int i = 0; i < 4; ++i) {
        #pragma unroll
        for (int j = 0; j < 4; ++j) {
            const int col = col0 + wn * 64 + j * 16 + r;
            const float bc = bias[col];
            #pragma unroll
            for (int t = 0; t < 4; ++t) {
                const int rrow = row0 + wm * 64 + i * 16 + kb * 4 + t;
                if (rrow < M) {
                    float v = acc[i][j][t] + bc;
                    if (EPI == 1) v = alpha * v + (1.f - alpha) * extra[rrow * 256 + col];
                    if (EPI == 2) v = tanhf(v + extra[rrow * 256 + col]);
                    cstore(C + rrow * ldc + col, v);
                }
            }
        }
    }
}

// =====================================================================
// msg_k: both relations fp8 K/V. Per-head 32-lane score groups with
// q hoisted to registers; register softmax (pre-divided); 8-slot
// accumulate with 8B fp8 loads; swizzled LDS partial-sum reduce.
// =====================================================================
template <int NE>
__device__ inline void rel_scores_f8(const unsigned char* __restrict__ kv, int ld, int koff,
                                     const int* __restrict__ sidx, int off, float scale,
                                     const float* __restrict__ qh, float* __restrict__ sc,
                                     int g, int l)
{
    constexpr int NL = NE / 32;
    float att[NL];
    #pragma unroll
    for (int t = 0; t < NL; ++t)
        att[t] = dot32f8(kv + (size_t)sidx[off + l + 32 * t] * ld + koff + g * 32, qh) * scale;
    float m = att[0];
    #pragma unroll
    for (int t = 1; t < NL; ++t) m = fmaxf(m, att[t]);
    #pragma unroll
    for (int o = 16; o > 0; o >>= 1) m = fmaxf(m, __shfl_xor(m, o));
    float ex[NL], s = 0.f;
    #pragma unroll
    for (int t = 0; t < NL; ++t) { ex[t] = __expf(att[t] - m); s += ex[t]; }
    #pragma unroll
    for (int o = 16; o > 0; o >>= 1) s += __shfl_xor(s, o);
    const float inv = 1.f / s;
    #pragma unroll
    for (int t = 0; t < NL; ++t) sc[(off + l + 32 * t) * 9 + g] = ex[t] * inv;
}

template <int NE>
__device__ inline void accum_f8(const unsigned char* __restrict__ kv, int ld, int voff,
                                const int* __restrict__ sidx, int off,
                                const float* __restrict__ sc,
                                int es, int ct, int h, float* __restrict__ acc)
{
    #pragma unroll
    for (int e = es; e < NE; e += 8) {
        const float w = sc[(off + e) * 9 + h];
        const uint2 u = *reinterpret_cast<const uint2*>(
            kv + (size_t)sidx[off + e] * ld + voff + ct * 8);
        float f[8];
        dec4(u.x, f); dec4(u.y, f + 4);
        #pragma unroll
        for (int k = 0; k < 8; ++k) acc[k] = fmaf(w, f[k], acc[k]);
    }
}

template <int NEA, int NEB>
__global__ __launch_bounds__(256) void msg_k(
    const short* __restrict__ q, int ldq,
    const unsigned char* __restrict__ kvA, int ldA, int koffA, int voffA,
    const int* __restrict__ srcA,
    const unsigned char* __restrict__ kvB, int ldB, int koffB, int voffB,
    const int* __restrict__ srcB,
    const float* __restrict__ relPri, int relA, int relB,
    short* __restrict__ out, int n_dst)
{
    constexpr int NET = NEA + NEB;
    const int j = blockIdx.x, tid = threadIdx.x;
    __shared__ float qsh[256];
    __shared__ int sidx[NET];
    __shared__ float sc[NET * 9];
    __shared__ float psA[8][256];
    __shared__ float psB[8][256];

    qsh[tid] = bfu((unsigned short)q[j * ldq + tid]);
    if (tid < NEA) sidx[tid] = srcA[j + tid * n_dst];
    else if (tid < NET) sidx[tid] = srcB[j + (tid - NEA) * n_dst];
    __syncthreads();

    const int g = tid >> 5, l = tid & 31;
    // hoist this head's q slice into registers (reused by every dot)
    float qr[32];
    #pragma unroll
    for (int c = 0; c < 8; ++c) {
        const float4 v = *reinterpret_cast<const float4*>(qsh + g * 32 + c * 4);
        qr[c * 4] = v.x; qr[c * 4 + 1] = v.y; qr[c * 4 + 2] = v.z; qr[c * 4 + 3] = v.w;
    }

    if constexpr (NEA == 16 && NEB == 16) {
        // doc: 32 lanes cover 16+16 edges, one dot per lane, uniform fp8 path
        const int isB = l >> 4;
        const unsigned char* base = isB ? kvB + koffB : kvA + koffA;
        const int ld = isB ? ldB : ldA;
        const float scale = relPri[(isB ? relB : relA) * 8 + g] * INV_SQRT_DK;
        const float att = dot32f8(base + (size_t)sidx[l] * ld + g * 32, qr) * scale;
        float m = att;
        #pragma unroll
        for (int o = 8; o > 0; o >>= 1) m = fmaxf(m, __shfl_xor(m, o));
        const float ex = __expf(att - m);
        float s = ex;
        #pragma unroll
        for (int o = 8; o > 0; o >>= 1) s += __shfl_xor(s, o);
        sc[l * 9 + g] = ex / s;
    } else {
        rel_scores_f8<NEA>(kvA, ldA, koffA, sidx, 0,
                           relPri[relA * 8 + g] * INV_SQRT_DK, qr, sc, g, l);
        rel_scores_f8<NEB>(kvB, ldB, koffB, sidx, NEA,
                           relPri[relB * 8 + g] * INV_SQRT_DK, qr, sc, g, l);
    }
    __syncthreads();

    const int es = tid >> 5, ct = tid & 31, hh = ct >> 2;
    float accA[8] = {}, accB[8] = {};
    accum_f8<NEA>(kvA, ldA, voffA, sidx, 0,   sc, es, ct, hh, accA);
    accum_f8<NEB>(kvB, ldB, voffB, sidx, NEA, sc, es, ct, hh, accB);
    const int sw = ct & 4;
    *reinterpret_cast<float4*>(&psA[es][(ct * 8) ^ sw])     = make_float4(accA[0], accA[1], accA[2], accA[3]);
    *reinterpret_cast<float4*>(&psA[es][(ct * 8 + 4) ^ sw]) = make_float4(accA[4], accA[5], accA[6], accA[7]);
    *reinterpret_cast<float4*>(&psB[es][(ct * 8) ^ sw])     = make_float4(accB[0], accB[1], accB[2], accB[3]);
    *reinterpret_cast<float4*>(&psB[es][(ct * 8 + 4) ^ sw]) = make_float4(accB[4], accB[5], accB[6], accB[7]);
    __syncthreads();

    float rA = 0.f, rB = 0.f;
    const int rp = tid ^ ((tid >> 3) & 4);
    #pragma unroll
    for (int e2 = 0; e2 < 8; ++e2) { rA += psA[e2][rp]; rB += psB[e2][rp]; }
    out[j * 256 + tid] = f2bf(0.5f * (fmaxf(rA, 0.f) + fmaxf(rB, 0.f)));
}

// =====================================================================
template <bool WB>
__global__ __launch_bounds__(256) void ln_k(
    float* __restrict__ data, const float* __restrict__ g,
    const float* __restrict__ b, int nrows, short* __restrict__ bfout)
{
    const int wid = threadIdx.x >> 6, lane = threadIdx.x & 63;
    const int row = blockIdx.x * 4 + wid;
    if (row >= nrows) return;
    float4 x = *reinterpret_cast<float4*>(data + row * 256 + lane * 4);
    float s  = x.x + x.y + x.z + x.w;
    float q2 = x.x * x.x + x.y * x.y + x.z * x.z + x.w * x.w;
    #pragma unroll
    for (int o = 32; o > 0; o >>= 1) { s += __shfl_xor(s, o); q2 += __shfl_xor(q2, o); }
    const float mu  = s * (1.f / 256.f);
    const float var = q2 * (1.f / 256.f) - mu * mu;
    const float rr = rsqrtf(var + 1e-5f);
    const float4 gg = *reinterpret_cast<const float4*>(g + lane * 4);
    const float4 bb = *reinterpret_cast<const float4*>(b + lane * 4);
    x.x = (x.x - mu) * rr * gg.x + bb.x;
    x.y = (x.y - mu) * rr * gg.y + bb.y;
    x.z = (x.z - mu) * rr * gg.z + bb.z;
    x.w = (x.w - mu) * rr * gg.w + bb.w;
    *reinterpret_cast<float4*>(data + row * 256 + lane * 4) = x;
    if (WB) {
        ushort4 u;
        u.x = (unsigned short)f2bf(x.x); u.y = (unsigned short)f2bf(x.y);
        u.z = (unsigned short)f2bf(x.z); u.w = (unsigned short)f2bf(x.w);
        *reinterpret_cast<ushort4*>((unsigned short*)bfout + row * 256 + lane * 4) = u;
    }
}

// =====================================================================
extern "C" void kernel_launch(void* const* d_in, const int* in_sizes, int n_in,
                              void* d_out, int out_size, void* d_ws, size_t ws_size,
                              hipStream_t stream)
{
    const float* feat_topic = (const float*)d_in[0];
    const float* feat_word  = (const float*)d_in[1];
    const float* feat_doc   = (const float*)d_in[2];
    const float* ht_prev    = (const float*)d_in[3];
    const float* Wk  = (const float*)d_in[4];
    const float* bk  = (const float*)d_in[5];
    const float* Wq  = (const float*)d_in[6];
    const float* bq  = (const float*)d_in[7];
    const float* Wv  = (const float*)d_in[8];
    const float* bv  = (const float*)d_in[9];
    const float* Wa  = (const float*)d_in[10];
    const float* ba  = (const float*)d_in[11];
    const float* ln_g = (const float*)d_in[12];
    const float* ln_b = (const float*)d_in[13];
    const float* skip = (const float*)d_in[14];
    const float* Wih  = (const float*)d_in[15];
    const float* Whh  = (const float*)d_in[16];
    const float* bih  = (const float*)d_in[17];
    const float* bhh  = (const float*)d_in[18];
    const float* rel_pri = (const float*)d_in[19];
    const float* rel_att = (const float*)d_in[20];
    const float* rel_msg = (const float*)d_in[21];
    const int* src_tt = (const int*)d_in[22];
    const int* src_wt = (const int*)d_in[24];
    const int* src_td = (const int*)d_in[26];
    const int* src_wd = (const int*)d_in[28];

    // ---- workspace layout ----
    short* B_t1 = (short*)d_ws;                 // 768*256
    short* B_w  = B_t1 + 196608;                // 1024*256
    short* B_t2 = B_w + 262144;                 // 512*256
    short* Wq2t = B_t2 + 131072;                // 5 x 256*256
    short* Whht = Wq2t + 65536;
    short* Wa0t = Whht + 65536;
    short* Wiht = Wa0t + 65536;
    short* Wa1t = Wiht + 65536;
    short* q_t  = Wa1t + 65536;                 // bf16 [2000][256]
    unsigned char* kv1 = (unsigned char*)(q_t + 512000);  // fp8 [2000][512]  K_tt|V_tt
    unsigned char* w8  = kv1 + 1024000;                   // fp8 [50000][1024] Kwt|Vwt|Kwd|Vwd
    unsigned char* kv2 = w8 + 51200000;                   // fp8 [2000][512]  K_td|V_td
    short* qd   = (short*)(kv2 + 1024000);      // bf16 [20000][256]
    short* ttop = qd + 5120000;                 // bf16 [2000][256]
    short* mixb = ttop + 512000;                // bf16 [2000][256]
    short* tdoc = mixb + 512000;                // bf16 [20000][256]
    short* xt2  = tdoc + 5120000;               // bf16 [2000][256]
    float* bias_t1 = (float*)(xt2 + 512000);    // 768
    float* bias_w  = bias_t1 + 768;             // 1024
    float* bias_t2 = bias_w + 1024;             // 512
    float* r2      = bias_t2 + 512;             // fp32 [2000][256]

    float* out_topic = (float*)d_out;
    float* out_doc   = out_topic + NT * 256;

    // ---- weight prep ----
    fold_kernel<<<dim3(64), 256, 0, stream>>>(Wk, bk, Wv, bv, rel_att, rel_msg,
                                              B_t1, B_w, B_t2, bias_t1, bias_w, bias_t2);
    TransP tp;
    tp.s[0] = Wq;            tp.d[0] = B_t1;   // Wq[topic]
    tp.s[1] = Wq + 131072;   tp.d[1] = Wq2t;   // Wq[doc]
    tp.s[2] = Whh;           tp.d[2] = Whht;
    tp.s[3] = Wih;           tp.d[3] = Wiht;
    tp.s[4] = Wa;            tp.d[4] = Wa0t;
    tp.s[5] = Wa + 65536;    tp.d[5] = Wa1t;
    wtrans6<<<dim3(256, 6), 256, 0, stream>>>(tp);
    copy_bias<<<dim3(1), 256, 0, stream>>>(bq, bias_t1);

    // ---- word GEMM (fp32 A reg-staged + XCD swizzle, fp8 out) ----
    gemm_lds<true, unsigned char, 0, true><<<dim3(8, 392), 256, 0, stream>>>(
        feat_word, B_w, bias_w, w8, NW, 1024, nullptr, nullptr, 0);

    // ---- remaining phase-1 projections ----
    gemm_lds<true, short, 0, false><<<dim3(2, 16), 256, 0, stream>>>(
        feat_topic, B_t1, bias_t1, q_t, NT, 256, nullptr, nullptr, 0);
    gemm_lds<true, unsigned char, 0, false><<<dim3(4, 16), 256, 0, stream>>>(
        feat_topic, B_t1 + 65536, bias_t1 + 256, kv1, NT, 512, nullptr, nullptr, 0);
    gemm_lds<true, short, 0, false><<<dim3(2, 157), 256, 0, stream>>>(
        feat_doc, Wq2t, bq + 512, qd, ND, 256, nullptr, nullptr, 0);
    gemm_lds<true, float, 0, false><<<dim3(2, 16), 256, 0, stream>>>(
        ht_prev, Whht, bhh, r2, NT, 256, nullptr, nullptr, 0);

    // ---- messages into topic (tt:64/dst, wt:128/dst, both fp8) ----
    msg_k<64, 128><<<dim3(NT), 256, 0, stream>>>(
        q_t, 256,
        kv1, 512, 0, 256, src_tt,
        w8, 1024, 0, 256, src_wt,
        rel_pri, 0, 1, ttop, NT);

    // ---- topic update: mix -> RNN tanh -> LN ----
    gemm_lds<false, short, 1, false><<<dim3(2, 16), 256, 0, stream>>>(
        ttop, Wa0t, ba, mixb, NT, 256, feat_topic, skip, 0);
    gemm_lds<false, float, 2, false><<<dim3(2, 16), 256, 0, stream>>>(
        mixb, Wiht, bih, out_topic, NT, 256, r2, nullptr, 0);
    ln_k<true><<<dim3(500), 256, 0, stream>>>(out_topic, ln_g, ln_b, NT, xt2);

    // ---- phase-2 topic projections (fp8 out) ----
    gemm_lds<false, unsigned char, 0, false><<<dim3(4, 16), 256, 0, stream>>>(
        xt2, B_t2, bias_t2, kv2, NT, 512, nullptr, nullptr, 0);

    // ---- messages into doc (td:16/dst, wd:16/dst, both fp8) ----
    msg_k<16, 16><<<dim3(ND), 256, 0, stream>>>(
        qd, 256,
        kv2, 512, 0, 256, src_td,
        w8, 1024, 512, 768, src_wd,
        rel_pri, 2, 3, tdoc, ND);

    // ---- doc update: mix -> LN ----
    gemm_lds<false, float, 1, false><<<dim3(2, 157), 256, 0, stream>>>(
        tdoc, Wa1t, ba + 256, out_doc, ND, 256, feat_doc, skip, 1);
    ln_k<false><<<dim3(5000), 256, 0, stream>>>(out_doc, ln_g + 256, ln_b + 256, ND, nullptr);
}